// Round 8
// baseline (2323.630 us; speedup 1.0000x reference)
//
#include <hip/hip_runtime.h>
#include <math.h>

#define BB 8      // batch
#define KCH 10    // Chebyshev order
#define GRD(n) ((int)(((n) + 255) / 256))

typedef __attribute__((ext_vector_type(8))) short bf16x8_t;
typedef __attribute__((ext_vector_type(4))) float f32x4_t;
typedef __attribute__((ext_vector_type(4))) unsigned short u16x4_t;

__device__ __forceinline__ float elu_f(float x){ return x > 0.f ? x : expf(x) - 1.f; }

// float -> bf16 (RNE)
__device__ __forceinline__ unsigned short f2bf(float f){
  unsigned int u = __float_as_uint(f);
  u += 0x7FFFu + ((u >> 16) & 1u);
  return (unsigned short)(u >> 16);
}
__device__ __forceinline__ float bf2f(unsigned short h){
  return __uint_as_float((unsigned int)h << 16);
}
__device__ __forceinline__ float join_bf(unsigned short h, unsigned short l){
  return bf2f(h) + bf2f(l);
}
__device__ __forceinline__ void split_bf(float v, unsigned short& h, unsigned short& l){
  h = f2bf(v);
  l = f2bf(v - bf2f(h));
}

// x input [B,V] fp32 -> x0 pair [2][V*B] (hi/lo planes)
__global__ void transpose_in(const float* __restrict__ x, unsigned short* __restrict__ x0,
                             int V){
  int i = blockIdx.x*256 + threadIdx.x;
  if (i < BB*V){
    int b = i / V, v = i - b*V;
    long N = (long)V*BB;
    unsigned short h, l;
    split_bf(x[i], h, l);
    x0[(long)v*BB + b] = h;
    x0[N + (long)v*BB + b] = l;
  }
}

// ---------------- CSR build (global atomics) ----------------

__global__ void zero_k(int* __restrict__ p, int n){
  int i = blockIdx.x*256 + threadIdx.x;
  if (i < n) p[i] = 0;
}

__global__ void hist_g(const int* __restrict__ rows, int* __restrict__ cnt, int E){
  int e = blockIdx.x*256 + threadIdx.x;
  if (e < E) atomicAdd(&cnt[rows[e]], 1);
}

__global__ void scan_blk(const int* __restrict__ cnt, int* __restrict__ rp,
                         int* __restrict__ bsum, int V){
  __shared__ int sh[1024];
  int tid = threadIdx.x;
  int i = blockIdx.x*1024 + tid;
  int v = (i < V) ? cnt[i] : 0;
  sh[tid] = v;
  __syncthreads();
  for (int off = 1; off < 1024; off <<= 1){
    int t = (tid >= off) ? sh[tid - off] : 0;
    __syncthreads();
    sh[tid] += t;
    __syncthreads();
  }
  if (i < V) rp[i] = sh[tid] - v;
  if (tid == 1023) bsum[blockIdx.x] = sh[1023];
}

__global__ void scan_top(int* __restrict__ bsum, int nb){
  if (threadIdx.x == 0){
    int run = 0;
    for (int b = 0; b < nb; b++){ int t = bsum[b]; bsum[b] = run; run += t; }
  }
}

__global__ void scan_add(int* __restrict__ rp, int* __restrict__ rpw,
                         const int* __restrict__ bsum, int V, int E){
  int i = blockIdx.x*256 + threadIdx.x;
  if (i < V){
    int v = rp[i] + bsum[i >> 10];
    rp[i] = v;
    rpw[i] = v;
  }
  if (i == 0) rp[V] = E;
}

__global__ void scatter_g(const int* __restrict__ rows, const int* __restrict__ cols,
                          const float* __restrict__ vals,
                          int* __restrict__ rpw, int* __restrict__ cs,
                          float* __restrict__ vs, int E){
  int e = blockIdx.x*256 + threadIdx.x;
  if (e < E){
    int r = rows[e];
    int pos = atomicAdd(&rpw[r], 1);
    if (pos >= 0 && pos < E){
      cs[pos] = cols[e];
      vs[pos] = vals[e];
    }
  }
}

// ---------------- SpMV on pair-format slices ----------------
// xin/xprev/xout: [2][N] ushort planes. 4 elems per thread.
__global__ __launch_bounds__(256) void spmv_pair(
    const int* __restrict__ rp, const int* __restrict__ cs, const float* __restrict__ vs,
    const unsigned short* __restrict__ xin, const unsigned short* __restrict__ xprev,
    unsigned short* __restrict__ xout, long N, int V, int lf4, float alpha, float beta){
  long t = (long)blockIdx.x*256 + threadIdx.x;
  if (t >= ((long)V << lf4)) return;
  int r  = (int)(t >> lf4);
  int f4 = (int)(t - ((long)r << lf4));
  long eb = t*4;
  int j0 = rp[r], j1 = rp[r+1];
  float a0 = 0.f, a1 = 0.f, a2 = 0.f, a3 = 0.f;
  for (int j = j0; j < j1; j++){
    int   c = cs[j];
    float v = vs[j];
    long ce = ((((long)c << lf4) + f4)) * 4;
    u16x4_t hx = *(const u16x4_t*)(xin + ce);
    u16x4_t lx = *(const u16x4_t*)(xin + N + ce);
    a0 = fmaf(v, join_bf(hx[0], lx[0]), a0);
    a1 = fmaf(v, join_bf(hx[1], lx[1]), a1);
    a2 = fmaf(v, join_bf(hx[2], lx[2]), a2);
    a3 = fmaf(v, join_bf(hx[3], lx[3]), a3);
  }
  float o0 = alpha*a0, o1 = alpha*a1, o2 = alpha*a2, o3 = alpha*a3;
  if (xprev){
    u16x4_t hp = *(const u16x4_t*)(xprev + eb);
    u16x4_t lp = *(const u16x4_t*)(xprev + N + eb);
    o0 = fmaf(beta, join_bf(hp[0], lp[0]), o0);
    o1 = fmaf(beta, join_bf(hp[1], lp[1]), o1);
    o2 = fmaf(beta, join_bf(hp[2], lp[2]), o2);
    o3 = fmaf(beta, join_bf(hp[3], lp[3]), o3);
  }
  u16x4_t ho, lo_;
  {
    unsigned short th, tl;
    split_bf(o0, th, tl); ho[0] = th; lo_[0] = tl;
    split_bf(o1, th, tl); ho[1] = th; lo_[1] = tl;
    split_bf(o2, th, tl); ho[2] = th; lo_[2] = tl;
    split_bf(o3, th, tl); ho[3] = th; lo_[3] = tl;
  }
  *(u16x4_t*)(xout + eb) = ho;
  *(u16x4_t*)(xout + N + eb) = lo_;
}

// ---------------- W fragment precompute (bf16 hi/lo, MFMA layout) ----------------
__global__ void wfrag_k(const float* __restrict__ w, bf16x8_t* __restrict__ fh,
                        bf16x8_t* __restrict__ fl, int KT, int CO){
  int t = blockIdx.x*256 + threadIdx.x;
  int NCT = CO >> 4;
  int total = (KT >> 5) * NCT * 64;
  if (t >= total) return;
  int lane = t & 63;
  int rest = t >> 6;
  int ct = rest % NCT;
  int c  = rest / NCT;
  int col = ct*16 + (lane & 15);
  int kb  = c*32 + (lane >> 4)*8;
  bf16x8_t h, l;
  #pragma unroll
  for (int i = 0; i < 8; i++){
    float v = w[(long)(kb + i)*CO + col];
    unsigned short hh, ll;
    split_bf(v, hh, ll);
    h[i] = (short)hh;
    l[i] = (short)ll;
  }
  fh[t] = h; fl[t] = l;
}

// ---------------- MFMA GEMM, k-split across KW waves (small-M shapes) --------
// A sources are pair-format [2][N]. C: f32 (acc RMW) OR (do_elu) pair-out CP.
template<int CI, int CO, int KW>
__global__ __launch_bounds__(KW*64) void gemm_mfma_ks(
    const unsigned short* __restrict__ X0, const unsigned short* __restrict__ AR,
    const bf16x8_t* __restrict__ fh, const bf16x8_t* __restrict__ fl,
    const float* __restrict__ bias, float* __restrict__ C,
    unsigned short* __restrict__ CP,
    int k0, int nk, int nfit, long N, int acc, int do_elu){
  constexpr int NCT = CO/16;
  constexpr int CPS = CI/32;
  __shared__ float red[KW][NCT][4][64];
  const int lane = threadIdx.x & 63;
  const int wv   = threadIdx.x >> 6;
  const long r0  = (long)blockIdx.x * 16;
  const int ra   = lane & 15;
  const int k8   = (lane >> 4)*8;
  const int c_off = k0*CPS;
  const int nch  = nk*CPS;
  const int c0 = (wv*nch)/KW, c1 = ((wv+1)*nch)/KW;

  f32x4_t accv[NCT];
  #pragma unroll
  for (int ct = 0; ct < NCT; ct++) accv[ct] = (f32x4_t){0.f,0.f,0.f,0.f};

  bf16x8_t A0h, A0l, A1h, A1l;
  auto loadA = [&](int ch, bf16x8_t &Ah, bf16x8_t &Al){
    int kk = ch / CPS;
    int cc = ch - kk*CPS;
    int k  = k0 + kk;
    const unsigned short* Xk = (k == 0) ? X0 : AR + (size_t)((k-1) % nfit)*2*N;
    const unsigned short* ap = Xk + (long)(r0 + ra)*CI + cc*32 + k8;
    Ah = *(const bf16x8_t*)ap;
    Al = *(const bf16x8_t*)(ap + N);
  };
  auto computeC = [&](bf16x8_t &Ah, bf16x8_t &Al, int ch){
    const long cb = ((long)(c_off + ch)*NCT)*64 + lane;
    #pragma unroll
    for (int ct = 0; ct < NCT; ct++){
      bf16x8_t wh = fh[cb + ct*64];
      bf16x8_t wl = fl[cb + ct*64];
      accv[ct] = __builtin_amdgcn_mfma_f32_16x16x32_bf16(Ah, wh, accv[ct], 0, 0, 0);
      accv[ct] = __builtin_amdgcn_mfma_f32_16x16x32_bf16(Al, wh, accv[ct], 0, 0, 0);
      accv[ct] = __builtin_amdgcn_mfma_f32_16x16x32_bf16(Ah, wl, accv[ct], 0, 0, 0);
    }
  };

  if (c0 < c1){
    loadA(c0, A0h, A0l);
    int ch = c0;
    while (true){
      if (ch + 1 < c1) loadA(ch + 1, A1h, A1l);
      computeC(A0h, A0l, ch);
      if (++ch >= c1) break;
      if (ch + 1 < c1) loadA(ch + 1, A0h, A0l);
      computeC(A1h, A1l, ch);
      if (++ch >= c1) break;
    }
  }

  #pragma unroll
  for (int ct = 0; ct < NCT; ct++)
    #pragma unroll
    for (int j = 0; j < 4; j++)
      red[wv][ct][j][lane] = accv[ct][j];
  __syncthreads();

  // C/D layout: col = lane&15, row = (lane>>4)*4 + j
  const int rl  = (lane >> 4)*4;
  const int cb2 = lane & 15;
  const long NC = (long)gridDim.x * 16 * CO;
  constexpr int CTW = NCT/KW;
  #pragma unroll
  for (int t = 0; t < CTW; t++){
    const int ct  = wv*CTW + t;
    const int col = ct*16 + cb2;
    const float bia = do_elu ? bias[col] : 0.f;
    #pragma unroll
    for (int j = 0; j < 4; j++){
      float v = red[0][ct][j][lane];
      #pragma unroll
      for (int w = 1; w < KW; w++) v += red[w][ct][j][lane];
      long idx = (r0 + rl + j)*CO + col;
      if (acc) v += C[idx];
      if (do_elu){
        v = elu_f(v + bia);
        unsigned short h, l;
        split_bf(v, h, l);
        CP[idx] = h; CP[NC + idx] = l;
      } else {
        C[idx] = v;
      }
    }
  }
}

// ---------------- MFMA GEMM, independent tiles (large-M shapes) ----------------
template<int CI, int CO, int MT, int TPB>
__global__ __launch_bounds__(TPB) void gemm_mfma(
    const unsigned short* __restrict__ X0, const unsigned short* __restrict__ AR,
    const bf16x8_t* __restrict__ fh, const bf16x8_t* __restrict__ fl,
    const float* __restrict__ bias, float* __restrict__ C,
    unsigned short* __restrict__ CP,
    int k0, int nk, int nfit, long N, int acc, int do_elu){
  constexpr int NCT = CO/16;
  constexpr int CPS = CI/32;
  constexpr int WPB = TPB/64;
  const int lane = threadIdx.x & 63;
  const int wv   = threadIdx.x >> 6;
  const long r0  = ((long)blockIdx.x*WPB + wv) * (16*MT);
  const int ra   = lane & 15;
  const int k8   = (lane >> 4)*8;
  const int c_off = k0*CPS;
  const int nch = nk*CPS;

  f32x4_t accv[MT][NCT];
  #pragma unroll
  for (int t = 0; t < MT; t++)
    #pragma unroll
    for (int ct = 0; ct < NCT; ct++) accv[t][ct] = (f32x4_t){0.f,0.f,0.f,0.f};

  bf16x8_t A0h[MT], A0l[MT], A1h[MT], A1l[MT];

  auto loadA = [&](int ch, bf16x8_t (&Ah)[MT], bf16x8_t (&Al)[MT]){
    int kk = ch / CPS;
    int cc = ch - kk*CPS;
    int k  = k0 + kk;
    const unsigned short* Xk = (k == 0) ? X0 : AR + (size_t)((k-1) % nfit)*2*N;
    const unsigned short* ap = Xk + (long)(r0 + ra)*CI + cc*32 + k8;
    #pragma unroll
    for (int t = 0; t < MT; t++){
      Ah[t] = *(const bf16x8_t*)(ap + (long)t*16*CI);
      Al[t] = *(const bf16x8_t*)(ap + (long)t*16*CI + N);
    }
  };

  auto computeC = [&](bf16x8_t (&Ah)[MT], bf16x8_t (&Al)[MT], int ch){
    const long cb = ((long)(c_off + ch)*NCT)*64 + lane;
    #pragma unroll
    for (int ct = 0; ct < NCT; ct++){
      bf16x8_t wh = fh[cb + ct*64];
      bf16x8_t wl = fl[cb + ct*64];
      #pragma unroll
      for (int t = 0; t < MT; t++){
        accv[t][ct] = __builtin_amdgcn_mfma_f32_16x16x32_bf16(Ah[t], wh, accv[t][ct], 0, 0, 0);
        accv[t][ct] = __builtin_amdgcn_mfma_f32_16x16x32_bf16(Al[t], wh, accv[t][ct], 0, 0, 0);
        accv[t][ct] = __builtin_amdgcn_mfma_f32_16x16x32_bf16(Ah[t], wl, accv[t][ct], 0, 0, 0);
      }
    }
  };

  loadA(0, A0h, A0l);
  int ch = 0;
  while (true){
    if (ch + 1 < nch) loadA(ch + 1, A1h, A1l);
    computeC(A0h, A0l, ch);
    if (++ch >= nch) break;
    if (ch + 1 < nch) loadA(ch + 1, A0h, A0l);
    computeC(A1h, A1l, ch);
    if (++ch >= nch) break;
  }

  const int rl  = (lane >> 4)*4;
  const int cb2 = lane & 15;
  const long NC = (long)gridDim.x * (WPB*16*MT) * CO;
  #pragma unroll
  for (int t = 0; t < MT; t++){
    #pragma unroll
    for (int ct = 0; ct < NCT; ct++){
      const int col = ct*16 + cb2;
      const float bia = do_elu ? bias[col] : 0.f;
      #pragma unroll
      for (int j = 0; j < 4; j++){
        long idx = (r0 + t*16 + rl + j)*CO + col;
        float v = accv[t][ct][j];
        if (acc) v += C[idx];
        if (do_elu){
          v = elu_f(v + bia);
          unsigned short h, l;
          split_bf(v, h, l);
          CP[idx] = h; CP[NC + idx] = l;
        } else {
          C[idx] = v;
        }
      }
    }
  }
}

// ---------------- VALU GEMM for CI==1 (level-0 conv1 only) ----------------
template<int CI, int CO, int RT>
__global__ __launch_bounds__(256) void gemm_multi(
    const unsigned short* __restrict__ X0, const unsigned short* __restrict__ AR,
    const float* __restrict__ W, const float* __restrict__ bias,
    float* __restrict__ C, unsigned short* __restrict__ CP,
    int k0, int nk, int nfit, long N, int acc, int do_elu){
  constexpr int TN = CO/16;
  constexpr int NW = CI*CO;
  extern __shared__ float ws[];

  const int tid = threadIdx.x;
  const int tc = tid & 15, tr = tid >> 4;
  const long r0 = (long)blockIdx.x*(16*RT) + (long)tr*RT;

  const float4* W4 = (const float4*)(W + (size_t)k0*NW);
  for (int i = tid; i < nk*NW/4; i += 256) ((float4*)ws)[i] = W4[i];
  __syncthreads();

  float accv[RT][TN];
  #pragma unroll
  for (int m = 0; m < RT; m++)
    #pragma unroll
    for (int j = 0; j < TN; j++) accv[m][j] = 0.f;

  #pragma unroll 1
  for (int kk = 0; kk < nk; kk++){
    int k = k0 + kk;
    const unsigned short* Ak = (k == 0) ? X0 : AR + (size_t)((k-1) % nfit)*2*N;
    const float* wsl = ws + (size_t)kk*NW;
    const unsigned short* Ar = Ak + r0;   // Ci==1: row-contiguous
    float am[RT];
    #pragma unroll
    for (int m = 0; m < RT; m += 4){
      u16x4_t h = *(const u16x4_t*)(Ar + m);
      u16x4_t l = *(const u16x4_t*)(Ar + N + m);
      am[m]   = join_bf(h[0], l[0]);
      am[m+1] = join_bf(h[1], l[1]);
      am[m+2] = join_bf(h[2], l[2]);
      am[m+3] = join_bf(h[3], l[3]);
    }
    const float* wr = &wsl[tc];
    #pragma unroll
    for (int j = 0; j < TN; j++){
      float wv = wr[j*16];
      #pragma unroll
      for (int m = 0; m < RT; m++)
        accv[m][j] = fmaf(am[m], wv, accv[m][j]);
    }
  }

  const long NC = (long)gridDim.x * (16*RT) * CO;
  #pragma unroll
  for (int m = 0; m < RT; m++){
    #pragma unroll
    for (int j = 0; j < TN; j++){
      int col = tc + j*16;
      long idx = (r0 + m)*CO + col;
      float v = accv[m][j];
      if (acc) v += C[idx];
      if (do_elu){
        v = elu_f(v + bias[col]);
        unsigned short h, l;
        split_bf(v, h, l);
        CP[idx] = h; CP[NC + idx] = l;
      } else {
        C[idx] = v;
      }
    }
  }
}

static void launch_gemm(const unsigned short* X0, const unsigned short* AR,
                        const bf16x8_t* fh, const bf16x8_t* fl,
                        const float* W, const float* bias, float* C, unsigned short* CP,
                        long M, int Ci, int Co, int k0, int nk, int nfit,
                        long N, int acc, int do_elu, hipStream_t st){
  if (Ci == 1){
    size_t sh = (size_t)nk * 32 * sizeof(float);
    gemm_multi<1,32,8><<<(int)(M/128), 256, sh, st>>>(
        X0, AR, W, bias, C, CP, k0, nk, nfit, N, acc, do_elu);
    return;
  }
  if (Ci == 32 && Co == 32){
    gemm_mfma<32,32,2,256><<<(int)(M/128), 256, 0, st>>>(
        X0, AR, fh, fl, bias, C, CP, k0, nk, nfit, N, acc, do_elu);
    return;
  }
#define GK(ci,co) \
  if (Ci == ci && Co == co){ \
    gemm_mfma_ks<ci,co,4><<<(int)(M/16), 256, 0, st>>>( \
        X0, AR, fh, fl, bias, C, CP, k0, nk, nfit, N, acc, do_elu); \
    return; }
  GK(32,64) GK(64,64) GK(64,128) GK(128,128)
#undef GK
}

// out2 (CBUF f32, [V,B,C] pre-bias) -> skip (d_out f32), pooled -> nxp (pair),
// optional pooled -> pool_out (d_out f32)
__global__ void epilogue_k(const float* __restrict__ out2, const float* __restrict__ bias,
                           float* __restrict__ skip_out, unsigned short* __restrict__ nxp,
                           float* __restrict__ pool_out, int V, int C){
  long t = (long)blockIdx.x*256 + threadIdx.x;
  long total = (long)(V/4)*BB*C;
  if (t >= total) return;
  int  c  = (int)(t % C);
  long bv = t / C;
  int  b  = (int)(bv % BB);
  int  v2 = (int)(bv / BB);
  float bia = bias[c];
  float s = 0.f;
  for (int j = 0; j < 4; j++){
    long v = (long)4*v2 + j;
    float val = elu_f(out2[(v*BB + b)*C + c] + bia);
    skip_out[((long)b*V + v)*C + c] = val;
    s += val;
  }
  s *= 0.25f;
  long idx = ((long)v2*BB + b)*C + c;
  unsigned short h, l;
  split_bf(s, h, l);
  nxp[idx] = h;
  nxp[total + idx] = l;
  if (pool_out) pool_out[((long)b*(V/4) + v2)*C + c] = s;
}

__global__ void guard_k(float* __restrict__ out0, int code){
  if (threadIdx.x == 0) out0[0] = 1.0e6f + (float)code;
}

// ---------------- host driver ----------------

static int ilog2(int x){ int l = 0; while ((1 << l) < x) l++; return l; }

// One ChebConv on pair-format inputs. outC = f32 partial buffer;
// CP != null (with bias) => final group writes pair-format (bias+ELU fused).
static void run_cheb(const unsigned short* x0, unsigned short* arena, long N, int nfit,
                     float* outC, unsigned short* CP, const float* w, const float* bias,
                     const bf16x8_t* fh, const bf16x8_t* fl,
                     int V, int Ci, int Co, const int* rp, const int* cs, const float* vs,
                     hipStream_t stream){
  long M = (long)V*BB;
  int F4 = BB*Ci/4;
  int lf4 = ilog2(F4);
  long n4 = (long)V*F4;

  int k0 = 0;
  int g = (KCH < nfit + 1) ? KCH : nfit + 1;
  int next_k = 1;
  while (k0 < KCH){
    int kend = k0 + g;
    for (int k = next_k; k < kend; k++){
      unsigned short* dst = arena + (size_t)((k-1) % nfit)*2*N;
      const unsigned short* src = (k >= 2) ? arena + (size_t)((k-2) % nfit)*2*N : x0;
      const unsigned short* prv = (k >= 3) ? arena + (size_t)((k-3) % nfit)*2*N
                                           : ((k == 2) ? x0 : nullptr);
      spmv_pair<<<GRD(n4), 256, 0, stream>>>(rp, cs, vs, src, prv, dst, N, V, lf4,
                                             (k == 1) ? 1.f : 2.f, (k == 1) ? 0.f : -1.f);
    }
    next_k = kend;
    int last = (kend == KCH) ? 1 : 0;
    launch_gemm(x0, arena, fh, fl, w, bias, outC, CP, M, Ci, Co, k0, g, nfit, N,
                (k0 > 0) ? 1 : 0, (CP && last) ? 1 : 0, stream);
    k0 = kend;
    g = (KCH - k0 < nfit) ? (KCH - k0) : nfit;
  }
}

extern "C" void kernel_launch(void* const* d_in, const int* in_sizes, int n_in,
                              void* d_out, int out_size, void* d_ws, size_t ws_size,
                              hipStream_t stream){
  const float* x_in  = (const float*)d_in[0];
  const float* w1[3] = {(const float*)d_in[1], (const float*)d_in[8],  (const float*)d_in[15]};
  const float* b1[3] = {(const float*)d_in[2], (const float*)d_in[9],  (const float*)d_in[16]};
  const float* w2[3] = {(const float*)d_in[3], (const float*)d_in[10], (const float*)d_in[17]};
  const float* b2[3] = {(const float*)d_in[4], (const float*)d_in[11], (const float*)d_in[18]};
  const int*  rows[3]= {(const int*)d_in[5],   (const int*)d_in[12],   (const int*)d_in[19]};
  const int*  cols[3]= {(const int*)d_in[6],   (const int*)d_in[13],   (const int*)d_in[20]};
  const float* vals[3]={(const float*)d_in[7], (const float*)d_in[14], (const float*)d_in[21]};
  float* out = (float*)d_out;

  const int V[3] = {49152, 12288, 3072};
  const int E[3] = {393216, 98304, 24576};
  const int Ci1[3] = {1, 32, 64};
  const int Co1[3] = {32, 64, 128};

  // ---- workspace layout (4-byte units) ----
  float* wsf = (float*)d_ws;
  size_t off = 0;
  const size_t BUFSZ = (size_t)49152 * BB * 32;   // 12,582,912 elems
  float* CBUF = wsf + off; off += BUFSZ;                       // f32 GEMM partials
  unsigned short* X0P   = (unsigned short*)(wsf + off); off += BUFSZ;   // conv2 x0 pair
  unsigned short* ARENA = (unsigned short*)(wsf + off); off += 3*BUFSZ; // slice arena pair
  unsigned short* NXP   = (unsigned short*)(wsf + off); off += (size_t)12288 * BB * 32;
  int* rp[3]; int* cs[3]; float* vsf[3];
  for (int i = 0; i < 3; i++){
    rp[i]  = (int*)(wsf + off); off += V[i] + 1;
    cs[i]  = (int*)(wsf + off); off += E[i];
    vsf[i] =        wsf + off;  off += E[i];
  }
  int* cntw = (int*)(wsf + off); off += 49152;
  int* bsum = (int*)(wsf + off); off += 64;
  int* rpw  = (int*)(wsf + off); off += 49152;
  off = (off + 3) & ~(size_t)3;                   // 16B-align fragment arena
  bf16x8_t* FR = (bf16x8_t*)(wsf + off);
  const long FS[5] = {1280, 2560, 5120, 10240, 20480};
  bf16x8_t *fh_[5], *fl_[5];
  {
    long fo = 0;
    for (int i = 0; i < 5; i++){ fh_[i] = FR + fo; fl_[i] = FR + fo + FS[i]; fo += 2*FS[i]; }
    off += (size_t)(2*(1280+2560+5120+10240+20480)) * 4;
  }
  if (ws_size < off * sizeof(float)) return;

  const long ARENA_C = (long)3*BUFSZ;   // arena capacity in elems (4B each)

  // ---- W fragments (hi/lo bf16, MFMA layout) — once per launch ----
  wfrag_k<<<GRD(FS[0]), 256, 0, stream>>>(w2[0], fh_[0], fl_[0],  320,  32);
  wfrag_k<<<GRD(FS[1]), 256, 0, stream>>>(w1[1], fh_[1], fl_[1],  320,  64);
  wfrag_k<<<GRD(FS[2]), 256, 0, stream>>>(w2[1], fh_[2], fl_[2],  640,  64);
  wfrag_k<<<GRD(FS[3]), 256, 0, stream>>>(w1[2], fh_[3], fl_[3],  640, 128);
  wfrag_k<<<GRD(FS[4]), 256, 0, stream>>>(w2[2], fh_[4], fl_[4], 1280, 128);

  // ---- CSR build per level ----
  for (int i = 0; i < 3; i++){
    zero_k   <<<GRD(V[i]), 256, 0, stream>>>(cntw, V[i]);
    hist_g   <<<GRD(E[i]), 256, 0, stream>>>(rows[i], cntw, E[i]);
    int nb = (V[i] + 1023) / 1024;
    scan_blk <<<nb, 1024, 0, stream>>>(cntw, rp[i], bsum, V[i]);
    scan_top <<<1, 64, 0, stream>>>(bsum, nb);
    scan_add <<<GRD(V[i]), 256, 0, stream>>>(rp[i], rpw, bsum, V[i], E[i]);
    scatter_g<<<GRD(E[i]), 256, 0, stream>>>(rows[i], cols[i], vals[i],
                                             rpw, cs[i], vsf[i], E[i]);
  }

  // ---- level 0 input: [B,V] -> pair [V,B,1] ----
  transpose_in<<<GRD(BB*V[0]), 256, 0, stream>>>(x_in, NXP, V[0]);

  const long OFF_OUT[4] = {0, 12582912, 18874368, 22020096};
  const int FH1[3] = {-1, 1, 3};   // frag index for w1 per level (-1 = VALU path)
  const int FH2[3] = { 0, 2, 4};   // frag index for w2 per level

  for (int lvl = 0; lvl < 3; lvl++){
    int Vv = V[lvl];
    int Ci = Ci1[lvl], Cm = Co1[lvl];

    // conv1: NXP -> X0P (pair; bias+ELU fused on last GEMM group)
    long N1 = (long)Vv*BB*Ci;
    int nf1 = (int)(ARENA_C / N1); if (nf1 > 9) nf1 = 9;
    const bf16x8_t* f1h = (FH1[lvl] >= 0) ? fh_[FH1[lvl]] : nullptr;
    const bf16x8_t* f1l = (FH1[lvl] >= 0) ? fl_[FH1[lvl]] : nullptr;
    run_cheb(NXP, ARENA, N1, nf1, CBUF, X0P, w1[lvl], b1[lvl], f1h, f1l,
             Vv, Ci, Cm, rp[lvl], cs[lvl], vsf[lvl], stream);

    // conv2: X0P -> CBUF (f32 raw; epilogue applies bias+ELU+pool)
    long N2 = (long)Vv*BB*Cm;
    int nf2 = (int)(ARENA_C / N2); if (nf2 > 9) nf2 = 9;
    run_cheb(X0P, ARENA, N2, nf2, CBUF, nullptr, w2[lvl], nullptr,
             fh_[FH2[lvl]], fl_[FH2[lvl]],
             Vv, Cm, Cm, rp[lvl], cs[lvl], vsf[lvl], stream);

    long n2 = (long)(Vv/4) * BB * Cm;
    float* pool_out = (lvl == 2) ? (out + OFF_OUT[3]) : (float*)nullptr;
    epilogue_k<<<GRD(n2), 256, 0, stream>>>(CBUF, b2[lvl],
                                            out + OFF_OUT[lvl], NXP, pool_out,
                                            Vv, Cm);
  }

  if (out_size != 22806528)
    guard_k<<<1, 64, 0, stream>>>(out, out_size % 4096);
}

// Round 9
// 2305.795 us; speedup vs baseline: 1.0077x; 1.0077x over previous
//
#include <hip/hip_runtime.h>
#include <math.h>

#define BB 8      // batch
#define KCH 10    // Chebyshev order
#define GRD(n) ((int)(((n) + 255) / 256))

typedef __attribute__((ext_vector_type(8))) short bf16x8_t;
typedef __attribute__((ext_vector_type(4))) float f32x4_t;

__device__ __forceinline__ float elu_f(float x){ return x > 0.f ? x : expf(x) - 1.f; }

// float -> bf16 (RNE)
__device__ __forceinline__ unsigned short f2bf(float f){
  unsigned int u = __float_as_uint(f);
  u += 0x7FFFu + ((u >> 16) & 1u);
  return (unsigned short)(u >> 16);
}

// x input is [B, V] fp32 -> x0 [V, B] fp32
__global__ void transpose_in(const float* __restrict__ x, float* __restrict__ x0, int V){
  int i = blockIdx.x*256 + threadIdx.x;
  if (i < BB*V){
    int b = i / V, v = i - b*V;
    x0[(long)v*BB + b] = x[i];
  }
}

// ---------------- CSR build (global atomics) ----------------

__global__ void zero_k(int* __restrict__ p, int n){
  int i = blockIdx.x*256 + threadIdx.x;
  if (i < n) p[i] = 0;
}

__global__ void hist_g(const int* __restrict__ rows, int* __restrict__ cnt, int E){
  int e = blockIdx.x*256 + threadIdx.x;
  if (e < E) atomicAdd(&cnt[rows[e]], 1);
}

__global__ void scan_blk(const int* __restrict__ cnt, int* __restrict__ rp,
                         int* __restrict__ bsum, int V){
  __shared__ int sh[1024];
  int tid = threadIdx.x;
  int i = blockIdx.x*1024 + tid;
  int v = (i < V) ? cnt[i] : 0;
  sh[tid] = v;
  __syncthreads();
  for (int off = 1; off < 1024; off <<= 1){
    int t = (tid >= off) ? sh[tid - off] : 0;
    __syncthreads();
    sh[tid] += t;
    __syncthreads();
  }
  if (i < V) rp[i] = sh[tid] - v;
  if (tid == 1023) bsum[blockIdx.x] = sh[1023];
}

__global__ void scan_top(int* __restrict__ bsum, int nb){
  if (threadIdx.x == 0){
    int run = 0;
    for (int b = 0; b < nb; b++){ int t = bsum[b]; bsum[b] = run; run += t; }
  }
}

__global__ void scan_add(int* __restrict__ rp, int* __restrict__ rpw,
                         const int* __restrict__ bsum, int V, int E){
  int i = blockIdx.x*256 + threadIdx.x;
  if (i < V){
    int v = rp[i] + bsum[i >> 10];
    rp[i] = v;
    rpw[i] = v;
  }
  if (i == 0) rp[V] = E;
}

__global__ void scatter_g(const int* __restrict__ rows, const int* __restrict__ cols,
                          const float* __restrict__ vals,
                          int* __restrict__ rpw, int* __restrict__ cs,
                          float* __restrict__ vs, int E){
  int e = blockIdx.x*256 + threadIdx.x;
  if (e < E){
    int r = rows[e];
    int pos = atomicAdd(&rpw[r], 1);
    if (pos >= 0 && pos < E){
      cs[pos] = cols[e];
      vs[pos] = vals[e];
    }
  }
}

// ---------------- SpMV: float4 row-gather ----------------
__global__ __launch_bounds__(256) void spmv_gather4(
    const int* __restrict__ rp, const int* __restrict__ cs, const float* __restrict__ vs,
    const float4* __restrict__ xin, const float4* __restrict__ xprev,
    float4* __restrict__ xout, int V, int lf4, float alpha, float beta){
  long t = (long)blockIdx.x*256 + threadIdx.x;
  if (t >= ((long)V << lf4)) return;
  int r  = (int)(t >> lf4);
  int f4 = (int)(t - ((long)r << lf4));
  int j0 = rp[r], j1 = rp[r+1];
  float ax = 0.f, ay = 0.f, az = 0.f, aw = 0.f;
  for (int j = j0; j < j1; j++){
    int   c = cs[j];
    float v = vs[j];
    float4 g = xin[((long)c << lf4) + f4];
    ax = fmaf(v, g.x, ax); ay = fmaf(v, g.y, ay);
    az = fmaf(v, g.z, az); aw = fmaf(v, g.w, aw);
  }
  float4 o;
  o.x = alpha*ax; o.y = alpha*ay; o.z = alpha*az; o.w = alpha*aw;
  if (xprev){
    float4 p = xprev[t];
    o.x = fmaf(beta, p.x, o.x); o.y = fmaf(beta, p.y, o.y);
    o.z = fmaf(beta, p.z, o.z); o.w = fmaf(beta, p.w, o.w);
  }
  xout[t] = o;
}

// ---------------- W fragment precompute (bf16 hi/lo, MFMA layout) ----------------
// Frag element (c, ct, lane, i) <- Wcat[c*32 + (lane>>4)*8 + i][ct*16 + (lane&15)]
// stored as short8 at index (c*NCT + ct)*64 + lane. KT = 10*CI (multiple of 32).
__global__ void wfrag_k(const float* __restrict__ w, bf16x8_t* __restrict__ fh,
                        bf16x8_t* __restrict__ fl, int KT, int CO){
  int t = blockIdx.x*256 + threadIdx.x;
  int NCT = CO >> 4;
  int total = (KT >> 5) * NCT * 64;
  if (t >= total) return;
  int lane = t & 63;
  int rest = t >> 6;
  int ct = rest % NCT;
  int c  = rest / NCT;
  int col = ct*16 + (lane & 15);
  int kb  = c*32 + (lane >> 4)*8;
  bf16x8_t h, l;
  #pragma unroll
  for (int i = 0; i < 8; i++){
    float v = w[(long)(kb + i)*CO + col];
    unsigned short hh = f2bf(v);
    float hf = __uint_as_float(((unsigned int)hh) << 16);
    h[i] = (short)hh;
    l[i] = (short)f2bf(v - hf);
  }
  fh[t] = h; fl[t] = l;
}

// ---------------- MFMA GEMM, k-split across KW waves, MT row-tiles ----------
// One (16*MT)-row tile per block; wave wv computes a contiguous chunk-range of
// the k-chunks into register partials; LDS reduce [KW][NCT][4][64] per row-tile;
// wave wv finalizes NCT/KW column-tiles. In-place C==X0 safe: all A reads
// precede the barrier, writes follow; blocks own disjoint rows.
template<int CI, int CO, int KW, int MT>
__global__ __launch_bounds__(KW*64) void gemm_mfma_ks(
    const float* X0, const float* __restrict__ AR,
    const bf16x8_t* __restrict__ fh, const bf16x8_t* __restrict__ fl,
    const float* __restrict__ bias, float* C,
    int k0, int nk, int nfit, long slice, int acc, int do_elu){
  constexpr int NCT = CO/16;
  constexpr int CPS = CI/32;
  __shared__ float red[KW][NCT][4][64];
  const int lane = threadIdx.x & 63;
  const int wv   = threadIdx.x >> 6;
  const long r0  = (long)blockIdx.x * (16*MT);
  const int ra   = lane & 15;
  const int k8   = (lane >> 4)*8;
  const int c_off = k0*CPS;
  const int nch  = nk*CPS;
  const int c0 = (wv*nch)/KW, c1 = ((wv+1)*nch)/KW;

  f32x4_t accv[MT][NCT];
  #pragma unroll
  for (int t = 0; t < MT; t++)
    #pragma unroll
    for (int ct = 0; ct < NCT; ct++) accv[t][ct] = (f32x4_t){0.f,0.f,0.f,0.f};

  float4 A0[MT][2], A1[MT][2];
  auto loadA = [&](int ch, float4 (&A)[MT][2]){
    int kk = ch / CPS;
    int cc = ch - kk*CPS;
    int k  = k0 + kk;
    const float* Xk = (k == 0) ? X0 : AR + (size_t)((k-1) % nfit)*slice;
    const float* ap = Xk + (long)(r0 + ra)*CI + cc*32 + k8;
    #pragma unroll
    for (int t = 0; t < MT; t++){
      A[t][0] = *(const float4*)(ap + (long)t*16*CI);
      A[t][1] = *(const float4*)(ap + (long)t*16*CI + 4);
    }
  };
  auto computeC = [&](float4 (&A)[MT][2], int ch){
    bf16x8_t ah[MT], al[MT];
    #pragma unroll
    for (int t = 0; t < MT; t++){
      float av[8] = {A[t][0].x, A[t][0].y, A[t][0].z, A[t][0].w,
                     A[t][1].x, A[t][1].y, A[t][1].z, A[t][1].w};
      #pragma unroll
      for (int i = 0; i < 8; i++){
        unsigned short hh = f2bf(av[i]);
        float hf = __uint_as_float(((unsigned int)hh) << 16);
        ah[t][i] = (short)hh;
        al[t][i] = (short)f2bf(av[i] - hf);
      }
    }
    const long cb = ((long)(c_off + ch)*NCT)*64 + lane;
    #pragma unroll
    for (int ct = 0; ct < NCT; ct++){
      bf16x8_t wh = fh[cb + ct*64];
      bf16x8_t wl = fl[cb + ct*64];
      #pragma unroll
      for (int t = 0; t < MT; t++){
        accv[t][ct] = __builtin_amdgcn_mfma_f32_16x16x32_bf16(ah[t], wh, accv[t][ct], 0, 0, 0);
        accv[t][ct] = __builtin_amdgcn_mfma_f32_16x16x32_bf16(al[t], wh, accv[t][ct], 0, 0, 0);
        accv[t][ct] = __builtin_amdgcn_mfma_f32_16x16x32_bf16(ah[t], wl, accv[t][ct], 0, 0, 0);
      }
    }
  };

  if (c0 < c1){
    loadA(c0, A0);
    int ch = c0;
    while (true){
      if (ch + 1 < c1) loadA(ch + 1, A1);
      computeC(A0, ch);
      if (++ch >= c1) break;
      if (ch + 1 < c1) loadA(ch + 1, A0);
      computeC(A1, ch);
      if (++ch >= c1) break;
    }
  }

  // C/D layout: col = lane&15, row = (lane>>4)*4 + j   [m89-verified]
  const int rl  = (lane >> 4)*4;
  const int cb2 = lane & 15;
  constexpr int CTW = NCT/KW;   // col-tiles per wave in epilogue
  #pragma unroll
  for (int mt = 0; mt < MT; mt++){
    if (mt) __syncthreads();
    #pragma unroll
    for (int ct = 0; ct < NCT; ct++)
      #pragma unroll
      for (int j = 0; j < 4; j++)
        red[wv][ct][j][lane] = accv[mt][ct][j];
    __syncthreads();
    #pragma unroll
    for (int t = 0; t < CTW; t++){
      const int ct  = wv*CTW + t;
      const int col = ct*16 + cb2;
      const float bia = do_elu ? bias[col] : 0.f;
      #pragma unroll
      for (int j = 0; j < 4; j++){
        float v = red[0][ct][j][lane];
        #pragma unroll
        for (int w = 1; w < KW; w++) v += red[w][ct][j][lane];
        float* cp = C + (r0 + mt*16 + rl + j)*CO + col;
        if (acc) v += *cp;
        if (do_elu) v = elu_f(v + bia);
        *cp = v;
      }
    }
  }
}

// ---------------- MFMA GEMM, independent tiles (large-M shapes) ----------------
template<int CI, int CO, int MT, int TPB>
__global__ __launch_bounds__(TPB) void gemm_mfma(
    const float* X0, const float* __restrict__ AR,
    const bf16x8_t* __restrict__ fh, const bf16x8_t* __restrict__ fl,
    const float* __restrict__ bias, float* C,
    int k0, int nk, int nfit, long slice, int acc, int do_elu){
  constexpr int NCT = CO/16;
  constexpr int CPS = CI/32;
  constexpr int WPB = TPB/64;
  const int lane = threadIdx.x & 63;
  const int wv   = threadIdx.x >> 6;
  const long r0  = ((long)blockIdx.x*WPB + wv) * (16*MT);
  const int ra   = lane & 15;
  const int k8   = (lane >> 4)*8;
  const int c_off = k0*CPS;
  const int nch = nk*CPS;

  f32x4_t accv[MT][NCT];
  #pragma unroll
  for (int t = 0; t < MT; t++)
    #pragma unroll
    for (int ct = 0; ct < NCT; ct++) accv[t][ct] = (f32x4_t){0.f,0.f,0.f,0.f};

  float4 Abuf0[MT][2], Abuf1[MT][2];

  auto loadA = [&](int ch, float4 (&A)[MT][2]){
    int kk = ch / CPS;
    int cc = ch - kk*CPS;
    int k  = k0 + kk;
    const float* Xk = (k == 0) ? X0 : AR + (size_t)((k-1) % nfit)*slice;
    const float* ap = Xk + (long)(r0 + ra)*CI + cc*32 + k8;
    #pragma unroll
    for (int t = 0; t < MT; t++){
      A[t][0] = *(const float4*)(ap + (long)t*16*CI);
      A[t][1] = *(const float4*)(ap + (long)t*16*CI + 4);
    }
  };

  auto computeC = [&](float4 (&A)[MT][2], int ch){
    bf16x8_t ah[MT], al[MT];
    #pragma unroll
    for (int t = 0; t < MT; t++){
      float av[8] = {A[t][0].x, A[t][0].y, A[t][0].z, A[t][0].w,
                     A[t][1].x, A[t][1].y, A[t][1].z, A[t][1].w};
      #pragma unroll
      for (int i = 0; i < 8; i++){
        unsigned short hh = f2bf(av[i]);
        float hf = __uint_as_float(((unsigned int)hh) << 16);
        ah[t][i] = (short)hh;
        al[t][i] = (short)f2bf(av[i] - hf);
      }
    }
    const long cb = ((long)(c_off + ch)*NCT)*64 + lane;
    #pragma unroll
    for (int ct = 0; ct < NCT; ct++){
      bf16x8_t wh = fh[cb + ct*64];
      bf16x8_t wl = fl[cb + ct*64];
      #pragma unroll
      for (int t = 0; t < MT; t++){
        accv[t][ct] = __builtin_amdgcn_mfma_f32_16x16x32_bf16(ah[t], wh, accv[t][ct], 0, 0, 0);
        accv[t][ct] = __builtin_amdgcn_mfma_f32_16x16x32_bf16(al[t], wh, accv[t][ct], 0, 0, 0);
        accv[t][ct] = __builtin_amdgcn_mfma_f32_16x16x32_bf16(ah[t], wl, accv[t][ct], 0, 0, 0);
      }
    }
  };

  loadA(0, Abuf0);
  int ch = 0;
  while (true){
    if (ch + 1 < nch) loadA(ch + 1, Abuf1);
    computeC(Abuf0, ch);
    if (++ch >= nch) break;
    if (ch + 1 < nch) loadA(ch + 1, Abuf0);
    computeC(Abuf1, ch);
    if (++ch >= nch) break;
  }

  const int rl  = (lane >> 4)*4;
  const int cb2 = lane & 15;
  #pragma unroll
  for (int t = 0; t < MT; t++){
    #pragma unroll
    for (int ct = 0; ct < NCT; ct++){
      const int col = ct*16 + cb2;
      const float bia = do_elu ? bias[col] : 0.f;
      #pragma unroll
      for (int j = 0; j < 4; j++){
        float* cp = C + (r0 + t*16 + rl + j)*CO + col;
        float v = accv[t][ct][j];
        if (acc) v += *cp;
        if (do_elu) v = elu_f(v + bia);
        *cp = v;
      }
    }
  }
}

// ---------------- VALU GEMM for CI==1 (level-0 conv1 only) ----------------
template<int CI, int CO, int RT>
__global__ __launch_bounds__(256) void gemm_multi(
    const float* X0, const float* __restrict__ AR,
    const float* __restrict__ W, const float* __restrict__ bias,
    float* C, int k0, int nk, int nfit, long slice, int acc, int do_elu){
  constexpr int TN = CO/16;
  constexpr int NW = CI*CO;
  extern __shared__ float ws[];

  const int tid = threadIdx.x;
  const int tc = tid & 15, tr = tid >> 4;
  const long r0 = (long)blockIdx.x*(16*RT) + (long)tr*RT;

  const float4* W4 = (const float4*)(W + (size_t)k0*NW);
  for (int i = tid; i < nk*NW/4; i += 256) ((float4*)ws)[i] = W4[i];
  __syncthreads();

  float accv[RT][TN];
  #pragma unroll
  for (int m = 0; m < RT; m++)
    #pragma unroll
    for (int j = 0; j < TN; j++) accv[m][j] = 0.f;

  #pragma unroll 1
  for (int kk = 0; kk < nk; kk++){
    int k = k0 + kk;
    const float* Ak = (k == 0) ? X0 : AR + (size_t)((k-1) % nfit)*slice;
    const float* wsl = ws + (size_t)kk*NW;
    const float* Ar = Ak + r0*CI;
    float am[RT];
    #pragma unroll
    for (int m = 0; m < RT; m += 4){
      float4 a = *(const float4*)(Ar + m);
      am[m] = a.x; am[m+1] = a.y; am[m+2] = a.z; am[m+3] = a.w;
    }
    const float* wr = &wsl[tc];
    #pragma unroll
    for (int j = 0; j < TN; j++){
      float wv = wr[j*16];
      #pragma unroll
      for (int m = 0; m < RT; m++)
        accv[m][j] = fmaf(am[m], wv, accv[m][j]);
    }
  }

  #pragma unroll
  for (int m = 0; m < RT; m++){
    float* Cr = C + (r0 + m)*CO;
    #pragma unroll
    for (int j = 0; j < TN; j++){
      int col = tc + j*16;
      float v = accv[m][j];
      if (acc) v += Cr[col];
      if (do_elu) v = elu_f(v + bias[col]);
      Cr[col] = v;
    }
  }
}

static void launch_gemm(const float* X0, const float* AR,
                        const bf16x8_t* fh, const bf16x8_t* fl,
                        const float* W, const float* bias, float* C,
                        long M, int Ci, int Co, int k0, int nk, int nfit,
                        long slice, int acc, int do_elu, hipStream_t st){
  if (Ci == 1){
    size_t sh = (size_t)nk * 32 * sizeof(float);
    gemm_multi<1,32,8><<<(int)(M/128), 256, sh, st>>>(
        X0, AR, W, bias, C, k0, nk, nfit, slice, acc, do_elu);
    return;
  }
  // large-M shape: independent 4-wave tiles, MT=4 (quarters W-fragment traffic)
  if (Ci == 32 && Co == 32){
    gemm_mfma<32,32,4,256><<<(int)(M/256), 256, 0, st>>>(
        X0, AR, fh, fl, bias, C, k0, nk, nfit, slice, acc, do_elu);
    return;
  }
  // small-M shapes: k-split across 4 waves, MT=2 row-tiles per block
#define GK(ci,co) \
  if (Ci == ci && Co == co){ \
    gemm_mfma_ks<ci,co,4,2><<<(int)(M/32), 256, 0, st>>>( \
        X0, AR, fh, fl, bias, C, k0, nk, nfit, slice, acc, do_elu); \
    return; }
  GK(32,64) GK(64,64) GK(64,128) GK(128,128)
#undef GK
}

// out2 [V,B,C] pre-bias -> skip (d_out, [B,V,C]), pooled -> nx [V/4,B,C],
// optional pooled -> pool_out (d_out, [B,V/4,C])
__global__ void epilogue_k(const float* __restrict__ out2, const float* __restrict__ bias,
                           float* __restrict__ skip_out, float* __restrict__ nx,
                           float* __restrict__ pool_out, int V, int C){
  long t = (long)blockIdx.x*256 + threadIdx.x;
  long total = (long)(V/4)*BB*C;
  if (t >= total) return;
  int  c  = (int)(t % C);
  long bv = t / C;
  int  b  = (int)(bv % BB);
  int  v2 = (int)(bv / BB);
  float bia = bias[c];
  float s = 0.f;
  for (int j = 0; j < 4; j++){
    long v = (long)4*v2 + j;
    float val = elu_f(out2[(v*BB + b)*C + c] + bia);
    skip_out[((long)b*V + v)*C + c] = val;
    s += val;
  }
  s *= 0.25f;
  nx[((long)v2*BB + b)*C + c] = s;
  if (pool_out) pool_out[((long)b*(V/4) + v2)*C + c] = s;
}

__global__ void guard_k(float* __restrict__ out0, int code){
  if (threadIdx.x == 0) out0[0] = 1.0e6f + (float)code;
}

// ---------------- host driver ----------------

static int ilog2(int x){ int l = 0; while ((1 << l) < x) l++; return l; }

static void run_cheb(const float* x0, float* arena, long slice, int nfit,
                     float* outC, const float* w, const float* bias,
                     const bf16x8_t* fh, const bf16x8_t* fl,
                     int V, int Ci, int Co, const int* rp, const int* cs, const float* vs,
                     hipStream_t stream){
  long M = (long)V*BB;
  int F4 = BB*Ci/4;
  int lf4 = ilog2(F4);
  long n4 = (long)V*F4;

  int k0 = 0;
  int g = (KCH < nfit + 1) ? KCH : nfit + 1;
  int next_k = 1;
  while (k0 < KCH){
    int kend = k0 + g;
    for (int k = next_k; k < kend; k++){
      float* dst = arena + (size_t)((k-1) % nfit)*slice;
      const float* src = (k >= 2) ? arena + (size_t)((k-2) % nfit)*slice : x0;
      const float* prv = (k >= 3) ? arena + (size_t)((k-3) % nfit)*slice
                                  : ((k == 2) ? x0 : nullptr);
      spmv_gather4<<<GRD(n4), 256, 0, stream>>>(rp, cs, vs, (const float4*)src,
                                                (const float4*)prv, (float4*)dst, V, lf4,
                                                (k == 1) ? 1.f : 2.f, (k == 1) ? 0.f : -1.f);
    }
    next_k = kend;
    launch_gemm(x0, arena, fh, fl, w, bias, outC, M, Ci, Co, k0, g, nfit, slice,
                (k0 > 0) ? 1 : 0, (bias && kend == KCH) ? 1 : 0, stream);
    k0 = kend;
    g = (KCH - k0 < nfit) ? (KCH - k0) : nfit;
  }
}

extern "C" void kernel_launch(void* const* d_in, const int* in_sizes, int n_in,
                              void* d_out, int out_size, void* d_ws, size_t ws_size,
                              hipStream_t stream){
  const float* x_in  = (const float*)d_in[0];
  const float* w1[3] = {(const float*)d_in[1], (const float*)d_in[8],  (const float*)d_in[15]};
  const float* b1[3] = {(const float*)d_in[2], (const float*)d_in[9],  (const float*)d_in[16]};
  const float* w2[3] = {(const float*)d_in[3], (const float*)d_in[10], (const float*)d_in[17]};
  const float* b2[3] = {(const float*)d_in[4], (const float*)d_in[11], (const float*)d_in[18]};
  const int*  rows[3]= {(const int*)d_in[5],   (const int*)d_in[12],   (const int*)d_in[19]};
  const int*  cols[3]= {(const int*)d_in[6],   (const int*)d_in[13],   (const int*)d_in[20]};
  const float* vals[3]={(const float*)d_in[7], (const float*)d_in[14], (const float*)d_in[21]};
  float* out = (float*)d_out;

  const int V[3] = {49152, 12288, 3072};
  const int E[3] = {393216, 98304, 24576};
  const int Ci1[3] = {1, 32, 64};
  const int Co1[3] = {32, 64, 128};

  // ---- workspace layout (fp32 units) ----
  float* wsf = (float*)d_ws;
  size_t off = 0;
  const size_t BUFSZ = (size_t)49152 * BB * 32;   // 12,582,912 floats
  float* BUF0 = wsf + off; off += BUFSZ;
  float* ARENA = wsf + off; off += 3*BUFSZ;       // contiguous slice arena
  float* NX   = wsf + off; off += (size_t)12288 * BB * 32;
  int* rp[3]; int* cs[3]; float* vsf[3];
  for (int i = 0; i < 3; i++){
    rp[i]  = (int*)(wsf + off); off += V[i] + 1;
    cs[i]  = (int*)(wsf + off); off += E[i];
    vsf[i] =        wsf + off;  off += E[i];
  }
  int* cntw = (int*)(wsf + off); off += 49152;
  int* bsum = (int*)(wsf + off); off += 64;
  int* rpw  = (int*)(wsf + off); off += 49152;
  off = (off + 3) & ~(size_t)3;                   // 16B-align fragment arena
  bf16x8_t* FR = (bf16x8_t*)(wsf + off);
  // frag sizes (short8 units): w2L0 1280, w1L1 2560, w2L1 5120, w1L2 10240, w2L2 20480
  const long FS[5] = {1280, 2560, 5120, 10240, 20480};
  bf16x8_t *fh_[5], *fl_[5];
  {
    long fo = 0;
    for (int i = 0; i < 5; i++){ fh_[i] = FR + fo; fl_[i] = FR + fo + FS[i]; fo += 2*FS[i]; }
    off += (size_t)(2*(1280+2560+5120+10240+20480)) * 4;   // short8 = 4 floats
  }
  if (ws_size < off * sizeof(float)) return;

  const long ARENA_F = (long)3*BUFSZ;

  // ---- W fragments (hi/lo bf16, MFMA layout) — once per launch ----
  wfrag_k<<<GRD(FS[0]), 256, 0, stream>>>(w2[0], fh_[0], fl_[0],  320,  32);
  wfrag_k<<<GRD(FS[1]), 256, 0, stream>>>(w1[1], fh_[1], fl_[1],  320,  64);
  wfrag_k<<<GRD(FS[2]), 256, 0, stream>>>(w2[1], fh_[2], fl_[2],  640,  64);
  wfrag_k<<<GRD(FS[3]), 256, 0, stream>>>(w1[2], fh_[3], fl_[3],  640, 128);
  wfrag_k<<<GRD(FS[4]), 256, 0, stream>>>(w2[2], fh_[4], fl_[4], 1280, 128);

  // ---- CSR build per level ----
  for (int i = 0; i < 3; i++){
    zero_k   <<<GRD(V[i]), 256, 0, stream>>>(cntw, V[i]);
    hist_g   <<<GRD(E[i]), 256, 0, stream>>>(rows[i], cntw, E[i]);
    int nb = (V[i] + 1023) / 1024;
    scan_blk <<<nb, 1024, 0, stream>>>(cntw, rp[i], bsum, V[i]);
    scan_top <<<1, 64, 0, stream>>>(bsum, nb);
    scan_add <<<GRD(V[i]), 256, 0, stream>>>(rp[i], rpw, bsum, V[i], E[i]);
    scatter_g<<<GRD(E[i]), 256, 0, stream>>>(rows[i], cols[i], vals[i],
                                             rpw, cs[i], vsf[i], E[i]);
  }

  // ---- level 0 input: [B,V] -> [V,B,1] ----
  transpose_in<<<GRD(BB*V[0]), 256, 0, stream>>>(x_in, NX, V[0]);

  const long OFF_OUT[4] = {0, 12582912, 18874368, 22020096};
  const int FH1[3] = {-1, 1, 3};   // frag index for w1 per level (-1 = VALU path)
  const int FH2[3] = { 0, 2, 4};   // frag index for w2 per level

  for (int lvl = 0; lvl < 3; lvl++){
    int Vv = V[lvl];
    int Ci = Ci1[lvl], Cm = Co1[lvl];

    // conv1: NX -> BUF0 (bias+ELU fused on last GEMM group)
    long slice1 = (long)Vv*BB*Ci;
    int nf1 = (int)(ARENA_F / slice1); if (nf1 > 9) nf1 = 9;
    const bf16x8_t* f1h = (FH1[lvl] >= 0) ? fh_[FH1[lvl]] : nullptr;
    const bf16x8_t* f1l = (FH1[lvl] >= 0) ? fl_[FH1[lvl]] : nullptr;
    run_cheb(NX, ARENA, slice1, nf1, BUF0, w1[lvl], b1[lvl], f1h, f1l,
             Vv, Ci, Cm, rp[lvl], cs[lvl], vsf[lvl], stream);

    // conv2: BUF0 -> BUF0 (in-place; per-block rows disjoint)
    long slice2 = (long)Vv*BB*Cm;
    int nf2 = (int)(ARENA_F / slice2); if (nf2 > 9) nf2 = 9;
    run_cheb(BUF0, ARENA, slice2, nf2, BUF0, w2[lvl], nullptr,
             fh_[FH2[lvl]], fl_[FH2[lvl]],
             Vv, Cm, Cm, rp[lvl], cs[lvl], vsf[lvl], stream);

    long n2 = (long)(Vv/4) * BB * Cm;
    float* pool_out = (lvl == 2) ? (out + OFF_OUT[3]) : (float*)nullptr;
    epilogue_k<<<GRD(n2), 256, 0, stream>>>(BUF0, b2[lvl],
                                            out + OFF_OUT[lvl], NX, pool_out,
                                            Vv, Cm);
  }

  if (out_size != 22806528)
    guard_k<<<1, 64, 0, stream>>>(out, out_size % 4096);
}

// Round 10
// 2296.940 us; speedup vs baseline: 1.0116x; 1.0039x over previous
//
#include <hip/hip_runtime.h>
#include <math.h>

#define BB 8      // batch
#define KCH 10    // Chebyshev order
#define GRD(n) ((int)(((n) + 255) / 256))

typedef __attribute__((ext_vector_type(8))) short bf16x8_t;
typedef __attribute__((ext_vector_type(4))) float f32x4_t;

__device__ __forceinline__ float elu_f(float x){ return x > 0.f ? x : expf(x) - 1.f; }

// float -> bf16 (RNE)
__device__ __forceinline__ unsigned short f2bf(float f){
  unsigned int u = __float_as_uint(f);
  u += 0x7FFFu + ((u >> 16) & 1u);
  return (unsigned short)(u >> 16);
}

// x input is [B, V] fp32 -> x0 [V, B] fp32
__global__ void transpose_in(const float* __restrict__ x, float* __restrict__ x0, int V){
  int i = blockIdx.x*256 + threadIdx.x;
  if (i < BB*V){
    int b = i / V, v = i - b*V;
    x0[(long)v*BB + b] = x[i];
  }
}

// ---------------- CSR build (global atomics) ----------------

__global__ void zero_k(int* __restrict__ p, int n){
  int i = blockIdx.x*256 + threadIdx.x;
  if (i < n) p[i] = 0;
}

__global__ void hist_g(const int* __restrict__ rows, int* __restrict__ cnt, int E){
  int e = blockIdx.x*256 + threadIdx.x;
  if (e < E) atomicAdd(&cnt[rows[e]], 1);
}

__global__ void scan_blk(const int* __restrict__ cnt, int* __restrict__ rp,
                         int* __restrict__ bsum, int V){
  __shared__ int sh[1024];
  int tid = threadIdx.x;
  int i = blockIdx.x*1024 + tid;
  int v = (i < V) ? cnt[i] : 0;
  sh[tid] = v;
  __syncthreads();
  for (int off = 1; off < 1024; off <<= 1){
    int t = (tid >= off) ? sh[tid - off] : 0;
    __syncthreads();
    sh[tid] += t;
    __syncthreads();
  }
  if (i < V) rp[i] = sh[tid] - v;
  if (tid == 1023) bsum[blockIdx.x] = sh[1023];
}

__global__ void scan_top(int* __restrict__ bsum, int nb){
  if (threadIdx.x == 0){
    int run = 0;
    for (int b = 0; b < nb; b++){ int t = bsum[b]; bsum[b] = run; run += t; }
  }
}

__global__ void scan_add(int* __restrict__ rp, int* __restrict__ rpw,
                         const int* __restrict__ bsum, int V, int E){
  int i = blockIdx.x*256 + threadIdx.x;
  if (i < V){
    int v = rp[i] + bsum[i >> 10];
    rp[i] = v;
    rpw[i] = v;
  }
  if (i == 0) rp[V] = E;
}

__global__ void scatter_g(const int* __restrict__ rows, const int* __restrict__ cols,
                          const float* __restrict__ vals,
                          int* __restrict__ rpw, int* __restrict__ cs,
                          float* __restrict__ vs, int E){
  int e = blockIdx.x*256 + threadIdx.x;
  if (e < E){
    int r = rows[e];
    int pos = atomicAdd(&rpw[r], 1);
    if (pos >= 0 && pos < E){
      cs[pos] = cols[e];
      vs[pos] = vals[e];
    }
  }
}

// ---------------- SpMV: float4 row-gather ----------------
__global__ __launch_bounds__(256) void spmv_gather4(
    const int* __restrict__ rp, const int* __restrict__ cs, const float* __restrict__ vs,
    const float4* __restrict__ xin, const float4* __restrict__ xprev,
    float4* __restrict__ xout, int V, int lf4, float alpha, float beta){
  long t = (long)blockIdx.x*256 + threadIdx.x;
  if (t >= ((long)V << lf4)) return;
  int r  = (int)(t >> lf4);
  int f4 = (int)(t - ((long)r << lf4));
  int j0 = rp[r], j1 = rp[r+1];
  float ax = 0.f, ay = 0.f, az = 0.f, aw = 0.f;
  for (int j = j0; j < j1; j++){
    int   c = cs[j];
    float v = vs[j];
    float4 g = xin[((long)c << lf4) + f4];
    ax = fmaf(v, g.x, ax); ay = fmaf(v, g.y, ay);
    az = fmaf(v, g.z, az); aw = fmaf(v, g.w, aw);
  }
  float4 o;
  o.x = alpha*ax; o.y = alpha*ay; o.z = alpha*az; o.w = alpha*aw;
  if (xprev){
    float4 p = xprev[t];
    o.x = fmaf(beta, p.x, o.x); o.y = fmaf(beta, p.y, o.y);
    o.z = fmaf(beta, p.z, o.z); o.w = fmaf(beta, p.w, o.w);
  }
  xout[t] = o;
}

// ---------------- W fragment precompute (bf16 hi/lo, MFMA layout) ----------------
// Frag element (c, ct, lane, i) <- Wcat[c*32 + (lane>>4)*8 + i][ct*16 + (lane&15)]
// stored as short8 at index (c*NCT + ct)*64 + lane. KT = 10*CI (multiple of 32).
__global__ void wfrag_k(const float* __restrict__ w, bf16x8_t* __restrict__ fh,
                        bf16x8_t* __restrict__ fl, int KT, int CO){
  int t = blockIdx.x*256 + threadIdx.x;
  int NCT = CO >> 4;
  int total = (KT >> 5) * NCT * 64;
  if (t >= total) return;
  int lane = t & 63;
  int rest = t >> 6;
  int ct = rest % NCT;
  int c  = rest / NCT;
  int col = ct*16 + (lane & 15);
  int kb  = c*32 + (lane >> 4)*8;
  bf16x8_t h, l;
  #pragma unroll
  for (int i = 0; i < 8; i++){
    float v = w[(long)(kb + i)*CO + col];
    unsigned short hh = f2bf(v);
    float hf = __uint_as_float(((unsigned int)hh) << 16);
    h[i] = (short)hh;
    l[i] = (short)f2bf(v - hf);
  }
  fh[t] = h; fl[t] = l;
}

// ---------------- MFMA GEMM, column-split across 4 waves (small-M shapes) ----
// One 16-row tile per block; wave wv owns CTW = NCT/4 column-tiles and walks
// ALL k-chunks, double-buffering BOTH A and its W fragments (depth-2 pipeline).
// No LDS. In-place C==X0 safe: __syncthreads (drains each wave's loads)
// precedes the C write; blocks own disjoint rows.
template<int CI, int CO>
__global__ __launch_bounds__(256) void gemm_mfma_cs(
    const float* X0, const float* __restrict__ AR,
    const bf16x8_t* __restrict__ fh, const bf16x8_t* __restrict__ fl,
    const float* __restrict__ bias, float* C,
    int k0, int nk, int nfit, long slice, int acc, int do_elu){
  constexpr int NCT = CO/16;
  constexpr int CTW = NCT/4;    // col-tiles per wave
  constexpr int CPS = CI/32;
  const int lane = threadIdx.x & 63;
  const int wv   = threadIdx.x >> 6;
  const long r0  = (long)blockIdx.x * 16;
  const int ra   = lane & 15;
  const int k8   = (lane >> 4)*8;
  const int c_off = k0*CPS;
  const int nch  = nk*CPS;
  const int ctbase = wv*CTW;

  f32x4_t accv[CTW];
  #pragma unroll
  for (int t = 0; t < CTW; t++) accv[t] = (f32x4_t){0.f,0.f,0.f,0.f};

  float4 A0[2], A1[2];
  bf16x8_t W0[CTW][2], W1[CTW][2];

  auto loadA = [&](int ch, float4 (&A)[2]){
    int kk = ch / CPS;
    int cc = ch - kk*CPS;
    int k  = k0 + kk;
    const float* Xk = (k == 0) ? X0 : AR + (size_t)((k-1) % nfit)*slice;
    const float* ap = Xk + (long)(r0 + ra)*CI + cc*32 + k8;
    A[0] = *(const float4*)(ap);
    A[1] = *(const float4*)(ap + 4);
  };
  auto loadW = [&](int ch, bf16x8_t (&W)[CTW][2]){
    const long cb = ((long)(c_off + ch)*NCT)*64 + lane;
    #pragma unroll
    for (int t = 0; t < CTW; t++){
      W[t][0] = fh[cb + (ctbase + t)*64];
      W[t][1] = fl[cb + (ctbase + t)*64];
    }
  };
  auto computeC = [&](float4 (&A)[2], bf16x8_t (&W)[CTW][2]){
    float av[8] = {A[0].x, A[0].y, A[0].z, A[0].w, A[1].x, A[1].y, A[1].z, A[1].w};
    bf16x8_t ah, al;
    #pragma unroll
    for (int i = 0; i < 8; i++){
      unsigned short hh = f2bf(av[i]);
      float hf = __uint_as_float(((unsigned int)hh) << 16);
      ah[i] = (short)hh;
      al[i] = (short)f2bf(av[i] - hf);
    }
    #pragma unroll
    for (int t = 0; t < CTW; t++){
      accv[t] = __builtin_amdgcn_mfma_f32_16x16x32_bf16(ah, W[t][0], accv[t], 0, 0, 0);
      accv[t] = __builtin_amdgcn_mfma_f32_16x16x32_bf16(al, W[t][0], accv[t], 0, 0, 0);
      accv[t] = __builtin_amdgcn_mfma_f32_16x16x32_bf16(ah, W[t][1], accv[t], 0, 0, 0);
    }
  };

  loadA(0, A0); loadW(0, W0);
  int ch = 0;
  while (true){
    if (ch + 1 < nch){ loadA(ch + 1, A1); loadW(ch + 1, W1); }
    computeC(A0, W0);
    if (++ch >= nch) break;
    if (ch + 1 < nch){ loadA(ch + 1, A0); loadW(ch + 1, W0); }
    computeC(A1, W1);
    if (++ch >= nch) break;
  }

  __syncthreads();   // all waves' A reads drained -> in-place C write safe

  // C/D layout: col = lane&15, row = (lane>>4)*4 + j   [m89-verified]
  const int rl  = (lane >> 4)*4;
  const int cb2 = lane & 15;
  #pragma unroll
  for (int t = 0; t < CTW; t++){
    const int col = (ctbase + t)*16 + cb2;
    const float bia = do_elu ? bias[col] : 0.f;
    #pragma unroll
    for (int j = 0; j < 4; j++){
      float* cp = C + (r0 + rl + j)*CO + col;
      float v = accv[t][j];
      if (acc) v += *cp;
      if (do_elu) v = elu_f(v + bia);
      *cp = v;
    }
  }
}

// ---------------- MFMA GEMM, independent tiles (large-M shapes) ----------------
template<int CI, int CO, int MT, int TPB>
__global__ __launch_bounds__(TPB) void gemm_mfma(
    const float* X0, const float* __restrict__ AR,
    const bf16x8_t* __restrict__ fh, const bf16x8_t* __restrict__ fl,
    const float* __restrict__ bias, float* C,
    int k0, int nk, int nfit, long slice, int acc, int do_elu){
  constexpr int NCT = CO/16;
  constexpr int CPS = CI/32;
  constexpr int WPB = TPB/64;
  const int lane = threadIdx.x & 63;
  const int wv   = threadIdx.x >> 6;
  const long r0  = ((long)blockIdx.x*WPB + wv) * (16*MT);
  const int ra   = lane & 15;
  const int k8   = (lane >> 4)*8;
  const int c_off = k0*CPS;
  const int nch = nk*CPS;

  f32x4_t accv[MT][NCT];
  #pragma unroll
  for (int t = 0; t < MT; t++)
    #pragma unroll
    for (int ct = 0; ct < NCT; ct++) accv[t][ct] = (f32x4_t){0.f,0.f,0.f,0.f};

  float4 Abuf0[MT][2], Abuf1[MT][2];

  auto loadA = [&](int ch, float4 (&A)[MT][2]){
    int kk = ch / CPS;
    int cc = ch - kk*CPS;
    int k  = k0 + kk;
    const float* Xk = (k == 0) ? X0 : AR + (size_t)((k-1) % nfit)*slice;
    const float* ap = Xk + (long)(r0 + ra)*CI + cc*32 + k8;
    #pragma unroll
    for (int t = 0; t < MT; t++){
      A[t][0] = *(const float4*)(ap + (long)t*16*CI);
      A[t][1] = *(const float4*)(ap + (long)t*16*CI + 4);
    }
  };

  auto computeC = [&](float4 (&A)[MT][2], int ch){
    bf16x8_t ah[MT], al[MT];
    #pragma unroll
    for (int t = 0; t < MT; t++){
      float av[8] = {A[t][0].x, A[t][0].y, A[t][0].z, A[t][0].w,
                     A[t][1].x, A[t][1].y, A[t][1].z, A[t][1].w};
      #pragma unroll
      for (int i = 0; i < 8; i++){
        unsigned short hh = f2bf(av[i]);
        float hf = __uint_as_float(((unsigned int)hh) << 16);
        ah[t][i] = (short)hh;
        al[t][i] = (short)f2bf(av[i] - hf);
      }
    }
    const long cb = ((long)(c_off + ch)*NCT)*64 + lane;
    #pragma unroll
    for (int ct = 0; ct < NCT; ct++){
      bf16x8_t wh = fh[cb + ct*64];
      bf16x8_t wl = fl[cb + ct*64];
      #pragma unroll
      for (int t = 0; t < MT; t++){
        accv[t][ct] = __builtin_amdgcn_mfma_f32_16x16x32_bf16(ah[t], wh, accv[t][ct], 0, 0, 0);
        accv[t][ct] = __builtin_amdgcn_mfma_f32_16x16x32_bf16(al[t], wh, accv[t][ct], 0, 0, 0);
        accv[t][ct] = __builtin_amdgcn_mfma_f32_16x16x32_bf16(ah[t], wl, accv[t][ct], 0, 0, 0);
      }
    }
  };

  loadA(0, Abuf0);
  int ch = 0;
  while (true){
    if (ch + 1 < nch) loadA(ch + 1, Abuf1);
    computeC(Abuf0, ch);
    if (++ch >= nch) break;
    if (ch + 1 < nch) loadA(ch + 1, Abuf0);
    computeC(Abuf1, ch);
    if (++ch >= nch) break;
  }

  const int rl  = (lane >> 4)*4;
  const int cb2 = lane & 15;
  #pragma unroll
  for (int t = 0; t < MT; t++){
    #pragma unroll
    for (int ct = 0; ct < NCT; ct++){
      const int col = ct*16 + cb2;
      const float bia = do_elu ? bias[col] : 0.f;
      #pragma unroll
      for (int j = 0; j < 4; j++){
        float* cp = C + (r0 + t*16 + rl + j)*CO + col;
        float v = accv[t][ct][j];
        if (acc) v += *cp;
        if (do_elu) v = elu_f(v + bia);
        *cp = v;
      }
    }
  }
}

// ---------------- VALU GEMM for CI==1 (level-0 conv1 only) ----------------
template<int CI, int CO, int RT>
__global__ __launch_bounds__(256) void gemm_multi(
    const float* X0, const float* __restrict__ AR,
    const float* __restrict__ W, const float* __restrict__ bias,
    float* C, int k0, int nk, int nfit, long slice, int acc, int do_elu){
  constexpr int TN = CO/16;
  constexpr int NW = CI*CO;
  extern __shared__ float ws[];

  const int tid = threadIdx.x;
  const int tc = tid & 15, tr = tid >> 4;
  const long r0 = (long)blockIdx.x*(16*RT) + (long)tr*RT;

  const float4* W4 = (const float4*)(W + (size_t)k0*NW);
  for (int i = tid; i < nk*NW/4; i += 256) ((float4*)ws)[i] = W4[i];
  __syncthreads();

  float accv[RT][TN];
  #pragma unroll
  for (int m = 0; m < RT; m++)
    #pragma unroll
    for (int j = 0; j < TN; j++) accv[m][j] = 0.f;

  #pragma unroll 1
  for (int kk = 0; kk < nk; kk++){
    int k = k0 + kk;
    const float* Ak = (k == 0) ? X0 : AR + (size_t)((k-1) % nfit)*slice;
    const float* wsl = ws + (size_t)kk*NW;
    const float* Ar = Ak + r0*CI;
    float am[RT];
    #pragma unroll
    for (int m = 0; m < RT; m += 4){
      float4 a = *(const float4*)(Ar + m);
      am[m] = a.x; am[m+1] = a.y; am[m+2] = a.z; am[m+3] = a.w;
    }
    const float* wr = &wsl[tc];
    #pragma unroll
    for (int j = 0; j < TN; j++){
      float wv = wr[j*16];
      #pragma unroll
      for (int m = 0; m < RT; m++)
        accv[m][j] = fmaf(am[m], wv, accv[m][j]);
    }
  }

  #pragma unroll
  for (int m = 0; m < RT; m++){
    float* Cr = C + (r0 + m)*CO;
    #pragma unroll
    for (int j = 0; j < TN; j++){
      int col = tc + j*16;
      float v = accv[m][j];
      if (acc) v += Cr[col];
      if (do_elu) v = elu_f(v + bias[col]);
      Cr[col] = v;
    }
  }
}

static void launch_gemm(const float* X0, const float* AR,
                        const bf16x8_t* fh, const bf16x8_t* fl,
                        const float* W, const float* bias, float* C,
                        long M, int Ci, int Co, int k0, int nk, int nfit,
                        long slice, int acc, int do_elu, hipStream_t st){
  if (Ci == 1){
    size_t sh = (size_t)nk * 32 * sizeof(float);
    gemm_multi<1,32,8><<<(int)(M/128), 256, sh, st>>>(
        X0, AR, W, bias, C, k0, nk, nfit, slice, acc, do_elu);
    return;
  }
  // large-M shape: independent 4-wave tiles, MT=2 (R6-best config)
  if (Ci == 32 && Co == 32){
    gemm_mfma<32,32,2,256><<<(int)(M/128), 256, 0, st>>>(
        X0, AR, fh, fl, bias, C, k0, nk, nfit, slice, acc, do_elu);
    return;
  }
  // small-M shapes: column-split across 4 waves, A+W double-buffered, no LDS
#define GK(ci,co) \
  if (Ci == ci && Co == co){ \
    gemm_mfma_cs<ci,co><<<(int)(M/16), 256, 0, st>>>( \
        X0, AR, fh, fl, bias, C, k0, nk, nfit, slice, acc, do_elu); \
    return; }
  GK(32,64) GK(64,64) GK(64,128) GK(128,128)
#undef GK
}

// out2 [V,B,C] pre-bias -> skip (d_out, [B,V,C]), pooled -> nx [V/4,B,C],
// optional pooled -> pool_out (d_out, [B,V/4,C])
__global__ void epilogue_k(const float* __restrict__ out2, const float* __restrict__ bias,
                           float* __restrict__ skip_out, float* __restrict__ nx,
                           float* __restrict__ pool_out, int V, int C){
  long t = (long)blockIdx.x*256 + threadIdx.x;
  long total = (long)(V/4)*BB*C;
  if (t >= total) return;
  int  c  = (int)(t % C);
  long bv = t / C;
  int  b  = (int)(bv % BB);
  int  v2 = (int)(bv / BB);
  float bia = bias[c];
  float s = 0.f;
  for (int j = 0; j < 4; j++){
    long v = (long)4*v2 + j;
    float val = elu_f(out2[(v*BB + b)*C + c] + bia);
    skip_out[((long)b*V + v)*C + c] = val;
    s += val;
  }
  s *= 0.25f;
  nx[((long)v2*BB + b)*C + c] = s;
  if (pool_out) pool_out[((long)b*(V/4) + v2)*C + c] = s;
}

__global__ void guard_k(float* __restrict__ out0, int code){
  if (threadIdx.x == 0) out0[0] = 1.0e6f + (float)code;
}

// ---------------- host driver ----------------

static int ilog2(int x){ int l = 0; while ((1 << l) < x) l++; return l; }

static void run_cheb(const float* x0, float* arena, long slice, int nfit,
                     float* outC, const float* w, const float* bias,
                     const bf16x8_t* fh, const bf16x8_t* fl,
                     int V, int Ci, int Co, const int* rp, const int* cs, const float* vs,
                     hipStream_t stream){
  long M = (long)V*BB;
  int F4 = BB*Ci/4;
  int lf4 = ilog2(F4);
  long n4 = (long)V*F4;

  int k0 = 0;
  int g = (KCH < nfit + 1) ? KCH : nfit + 1;
  int next_k = 1;
  while (k0 < KCH){
    int kend = k0 + g;
    for (int k = next_k; k < kend; k++){
      float* dst = arena + (size_t)((k-1) % nfit)*slice;
      const float* src = (k >= 2) ? arena + (size_t)((k-2) % nfit)*slice : x0;
      const float* prv = (k >= 3) ? arena + (size_t)((k-3) % nfit)*slice
                                  : ((k == 2) ? x0 : nullptr);
      spmv_gather4<<<GRD(n4), 256, 0, stream>>>(rp, cs, vs, (const float4*)src,
                                                (const float4*)prv, (float4*)dst, V, lf4,
                                                (k == 1) ? 1.f : 2.f, (k == 1) ? 0.f : -1.f);
    }
    next_k = kend;
    launch_gemm(x0, arena, fh, fl, w, bias, outC, M, Ci, Co, k0, g, nfit, slice,
                (k0 > 0) ? 1 : 0, (bias && kend == KCH) ? 1 : 0, stream);
    k0 = kend;
    g = (KCH - k0 < nfit) ? (KCH - k0) : nfit;
  }
}

extern "C" void kernel_launch(void* const* d_in, const int* in_sizes, int n_in,
                              void* d_out, int out_size, void* d_ws, size_t ws_size,
                              hipStream_t stream){
  const float* x_in  = (const float*)d_in[0];
  const float* w1[3] = {(const float*)d_in[1], (const float*)d_in[8],  (const float*)d_in[15]};
  const float* b1[3] = {(const float*)d_in[2], (const float*)d_in[9],  (const float*)d_in[16]};
  const float* w2[3] = {(const float*)d_in[3], (const float*)d_in[10], (const float*)d_in[17]};
  const float* b2[3] = {(const float*)d_in[4], (const float*)d_in[11], (const float*)d_in[18]};
  const int*  rows[3]= {(const int*)d_in[5],   (const int*)d_in[12],   (const int*)d_in[19]};
  const int*  cols[3]= {(const int*)d_in[6],   (const int*)d_in[13],   (const int*)d_in[20]};
  const float* vals[3]={(const float*)d_in[7], (const float*)d_in[14], (const float*)d_in[21]};
  float* out = (float*)d_out;

  const int V[3] = {49152, 12288, 3072};
  const int E[3] = {393216, 98304, 24576};
  const int Ci1[3] = {1, 32, 64};
  const int Co1[3] = {32, 64, 128};

  // ---- workspace layout (fp32 units) ----
  float* wsf = (float*)d_ws;
  size_t off = 0;
  const size_t BUFSZ = (size_t)49152 * BB * 32;   // 12,582,912 floats
  float* BUF0 = wsf + off; off += BUFSZ;
  float* ARENA = wsf + off; off += 3*BUFSZ;       // contiguous slice arena
  float* NX   = wsf + off; off += (size_t)12288 * BB * 32;
  int* rp[3]; int* cs[3]; float* vsf[3];
  for (int i = 0; i < 3; i++){
    rp[i]  = (int*)(wsf + off); off += V[i] + 1;
    cs[i]  = (int*)(wsf + off); off += E[i];
    vsf[i] =        wsf + off;  off += E[i];
  }
  int* cntw = (int*)(wsf + off); off += 49152;
  int* bsum = (int*)(wsf + off); off += 64;
  int* rpw  = (int*)(wsf + off); off += 49152;
  off = (off + 3) & ~(size_t)3;                   // 16B-align fragment arena
  bf16x8_t* FR = (bf16x8_t*)(wsf + off);
  // frag sizes (short8 units): w2L0 1280, w1L1 2560, w2L1 5120, w1L2 10240, w2L2 20480
  const long FS[5] = {1280, 2560, 5120, 10240, 20480};
  bf16x8_t *fh_[5], *fl_[5];
  {
    long fo = 0;
    for (int i = 0; i < 5; i++){ fh_[i] = FR + fo; fl_[i] = FR + fo + FS[i]; fo += 2*FS[i]; }
    off += (size_t)(2*(1280+2560+5120+10240+20480)) * 4;   // short8 = 4 floats
  }
  if (ws_size < off * sizeof(float)) return;

  const long ARENA_F = (long)3*BUFSZ;

  // ---- W fragments (hi/lo bf16, MFMA layout) — once per launch ----
  wfrag_k<<<GRD(FS[0]), 256, 0, stream>>>(w2[0], fh_[0], fl_[0],  320,  32);
  wfrag_k<<<GRD(FS[1]), 256, 0, stream>>>(w1[1], fh_[1], fl_[1],  320,  64);
  wfrag_k<<<GRD(FS[2]), 256, 0, stream>>>(w2[1], fh_[2], fl_[2],  640,  64);
  wfrag_k<<<GRD(FS[3]), 256, 0, stream>>>(w1[2], fh_[3], fl_[3],  640, 128);
  wfrag_k<<<GRD(FS[4]), 256, 0, stream>>>(w2[2], fh_[4], fl_[4], 1280, 128);

  // ---- CSR build per level ----
  for (int i = 0; i < 3; i++){
    zero_k   <<<GRD(V[i]), 256, 0, stream>>>(cntw, V[i]);
    hist_g   <<<GRD(E[i]), 256, 0, stream>>>(rows[i], cntw, E[i]);
    int nb = (V[i] + 1023) / 1024;
    scan_blk <<<nb, 1024, 0, stream>>>(cntw, rp[i], bsum, V[i]);
    scan_top <<<1, 64, 0, stream>>>(bsum, nb);
    scan_add <<<GRD(V[i]), 256, 0, stream>>>(rp[i], rpw, bsum, V[i], E[i]);
    scatter_g<<<GRD(E[i]), 256, 0, stream>>>(rows[i], cols[i], vals[i],
                                             rpw, cs[i], vsf[i], E[i]);
  }

  // ---- level 0 input: [B,V] -> [V,B,1] ----
  transpose_in<<<GRD(BB*V[0]), 256, 0, stream>>>(x_in, NX, V[0]);

  const long OFF_OUT[4] = {0, 12582912, 18874368, 22020096};
  const int FH1[3] = {-1, 1, 3};   // frag index for w1 per level (-1 = VALU path)
  const int FH2[3] = { 0, 2, 4};   // frag index for w2 per level

  for (int lvl = 0; lvl < 3; lvl++){
    int Vv = V[lvl];
    int Ci = Ci1[lvl], Cm = Co1[lvl];

    // conv1: NX -> BUF0 (bias+ELU fused on last GEMM group)
    long slice1 = (long)Vv*BB*Ci;
    int nf1 = (int)(ARENA_F / slice1); if (nf1 > 9) nf1 = 9;
    const bf16x8_t* f1h = (FH1[lvl] >= 0) ? fh_[FH1[lvl]] : nullptr;
    const bf16x8_t* f1l = (FH1[lvl] >= 0) ? fl_[FH1[lvl]] : nullptr;
    run_cheb(NX, ARENA, slice1, nf1, BUF0, w1[lvl], b1[lvl], f1h, f1l,
             Vv, Ci, Cm, rp[lvl], cs[lvl], vsf[lvl], stream);

    // conv2: BUF0 -> BUF0 (in-place; per-block rows disjoint)
    long slice2 = (long)Vv*BB*Cm;
    int nf2 = (int)(ARENA_F / slice2); if (nf2 > 9) nf2 = 9;
    run_cheb(BUF0, ARENA, slice2, nf2, BUF0, w2[lvl], nullptr,
             fh_[FH2[lvl]], fl_[FH2[lvl]],
             Vv, Cm, Cm, rp[lvl], cs[lvl], vsf[lvl], stream);

    long n2 = (long)(Vv/4) * BB * Cm;
    float* pool_out = (lvl == 2) ? (out + OFF_OUT[3]) : (float*)nullptr;
    epilogue_k<<<GRD(n2), 256, 0, stream>>>(BUF0, b2[lvl],
                                            out + OFF_OUT[lvl], NX, pool_out,
                                            Vv, Cm);
  }

  if (out_size != 22806528)
    guard_k<<<1, 64, 0, stream>>>(out, out_size % 4096);
}

// Round 11
// 2239.417 us; speedup vs baseline: 1.0376x; 1.0257x over previous
//
#include <hip/hip_runtime.h>
#include <math.h>

#define BB 8      // batch
#define KCH 10    // Chebyshev order
#define GRD(n) ((int)(((n) + 255) / 256))

typedef __attribute__((ext_vector_type(8))) short bf16x8_t;
typedef __attribute__((ext_vector_type(4))) float f32x4_t;

__device__ __forceinline__ float elu_f(float x){ return x > 0.f ? x : expf(x) - 1.f; }

// float -> bf16 (RNE)
__device__ __forceinline__ unsigned short f2bf(float f){
  unsigned int u = __float_as_uint(f);
  u += 0x7FFFu + ((u >> 16) & 1u);
  return (unsigned short)(u >> 16);
}

// x input is [B, V] fp32 -> x0 [V, B] fp32
__global__ void transpose_in(const float* __restrict__ x, float* __restrict__ x0, int V){
  int i = blockIdx.x*256 + threadIdx.x;
  if (i < BB*V){
    int b = i / V, v = i - b*V;
    x0[(long)v*BB + b] = x[i];
  }
}

// ---------------- CSR build (global atomics) ----------------

__global__ void zero_k(int* __restrict__ p, int n){
  int i = blockIdx.x*256 + threadIdx.x;
  if (i < n) p[i] = 0;
}

__global__ void hist_g(const int* __restrict__ rows, int* __restrict__ cnt, int E){
  int e = blockIdx.x*256 + threadIdx.x;
  if (e < E) atomicAdd(&cnt[rows[e]], 1);
}

__global__ void scan_blk(const int* __restrict__ cnt, int* __restrict__ rp,
                         int* __restrict__ bsum, int V){
  __shared__ int sh[1024];
  int tid = threadIdx.x;
  int i = blockIdx.x*1024 + tid;
  int v = (i < V) ? cnt[i] : 0;
  sh[tid] = v;
  __syncthreads();
  for (int off = 1; off < 1024; off <<= 1){
    int t = (tid >= off) ? sh[tid - off] : 0;
    __syncthreads();
    sh[tid] += t;
    __syncthreads();
  }
  if (i < V) rp[i] = sh[tid] - v;
  if (tid == 1023) bsum[blockIdx.x] = sh[1023];
}

__global__ void scan_top(int* __restrict__ bsum, int nb){
  if (threadIdx.x == 0){
    int run = 0;
    for (int b = 0; b < nb; b++){ int t = bsum[b]; bsum[b] = run; run += t; }
  }
}

__global__ void scan_add(int* __restrict__ rp, int* __restrict__ rpw,
                         const int* __restrict__ bsum, int V, int E){
  int i = blockIdx.x*256 + threadIdx.x;
  if (i < V){
    int v = rp[i] + bsum[i >> 10];
    rp[i] = v;
    rpw[i] = v;
  }
  if (i == 0) rp[V] = E;
}

__global__ void scatter_g(const int* __restrict__ rows, const int* __restrict__ cols,
                          const float* __restrict__ vals,
                          int* __restrict__ rpw, int* __restrict__ cs,
                          float* __restrict__ vs, int E){
  int e = blockIdx.x*256 + threadIdx.x;
  if (e < E){
    int r = rows[e];
    int pos = atomicAdd(&rpw[r], 1);
    if (pos >= 0 && pos < E){
      cs[pos] = cols[e];
      vs[pos] = vals[e];
    }
  }
}

// ---------------- SpMV: float4 row-gather ----------------
__global__ __launch_bounds__(256) void spmv_gather4(
    const int* __restrict__ rp, const int* __restrict__ cs, const float* __restrict__ vs,
    const float4* __restrict__ xin, const float4* __restrict__ xprev,
    float4* __restrict__ xout, int V, int lf4, float alpha, float beta){
  long t = (long)blockIdx.x*256 + threadIdx.x;
  if (t >= ((long)V << lf4)) return;
  int r  = (int)(t >> lf4);
  int f4 = (int)(t - ((long)r << lf4));
  int j0 = rp[r], j1 = rp[r+1];
  float ax = 0.f, ay = 0.f, az = 0.f, aw = 0.f;
  for (int j = j0; j < j1; j++){
    int   c = cs[j];
    float v = vs[j];
    float4 g = xin[((long)c << lf4) + f4];
    ax = fmaf(v, g.x, ax); ay = fmaf(v, g.y, ay);
    az = fmaf(v, g.z, az); aw = fmaf(v, g.w, aw);
  }
  float4 o;
  o.x = alpha*ax; o.y = alpha*ay; o.z = alpha*az; o.w = alpha*aw;
  if (xprev){
    float4 p = xprev[t];
    o.x = fmaf(beta, p.x, o.x); o.y = fmaf(beta, p.y, o.y);
    o.z = fmaf(beta, p.z, o.z); o.w = fmaf(beta, p.w, o.w);
  }
  xout[t] = o;
}

// ---------------- W fragment precompute (bf16 hi/lo, MFMA layout) ----------------
// Frag element (c, ct, lane, i) <- Wcat[c*32 + (lane>>4)*8 + i][ct*16 + (lane&15)]
// stored as short8 at index (c*NCT + ct)*64 + lane. KT = 10*CI (multiple of 32).
__global__ void wfrag_k(const float* __restrict__ w, bf16x8_t* __restrict__ fh,
                        bf16x8_t* __restrict__ fl, int KT, int CO){
  int t = blockIdx.x*256 + threadIdx.x;
  int NCT = CO >> 4;
  int total = (KT >> 5) * NCT * 64;
  if (t >= total) return;
  int lane = t & 63;
  int rest = t >> 6;
  int ct = rest % NCT;
  int c  = rest / NCT;
  int col = ct*16 + (lane & 15);
  int kb  = c*32 + (lane >> 4)*8;
  bf16x8_t h, l;
  #pragma unroll
  for (int i = 0; i < 8; i++){
    float v = w[(long)(kb + i)*CO + col];
    unsigned short hh = f2bf(v);
    float hf = __uint_as_float(((unsigned int)hh) << 16);
    h[i] = (short)hh;
    l[i] = (short)f2bf(v - hf);
  }
  fh[t] = h; fl[t] = l;
}

// ---------------- MFMA GEMM, row-split waves + LDS-staged W (small-M) --------
// 4 waves per block, wave wv owns rows r0+wv*16 (block covers 64 rows).
// W fragments for each k-chunk staged once per block into LDS (double-buffered;
// global->reg issued one chunk ahead, reg->LDS written after compute). Each
// wave converts only its own A. One barrier per chunk. In-place C==X0 safe:
// a wave reads only its own 16 rows (all chunks) before writing them.
template<int CI, int CO>
__global__ __launch_bounds__(256) void gemm_mfma_rs(
    const float* X0, const float* __restrict__ AR,
    const bf16x8_t* __restrict__ fh, const bf16x8_t* __restrict__ fl,
    const float* __restrict__ bias, float* C,
    int k0, int nk, int nfit, long slice, int acc, int do_elu){
  constexpr int NCT = CO/16;
  constexpr int CPS = CI/32;
  constexpr int FPC = 2*NCT;          // fragments per chunk (fh then fl), 1KB each
  constexpr int LPT = FPC*64/256;     // bf16x8 loads per thread per chunk
  __shared__ bf16x8_t wbuf[2][FPC][64];
  const int tid  = threadIdx.x;
  const int lane = tid & 63;
  const int wv   = tid >> 6;
  const long r0  = ((long)blockIdx.x*4 + wv) * 16;
  const int ra   = lane & 15;
  const int k8   = (lane >> 4)*8;
  const int c_off = k0*CPS;
  const int nch  = nk*CPS;

  f32x4_t accv[NCT];
  #pragma unroll
  for (int ct = 0; ct < NCT; ct++) accv[ct] = (f32x4_t){0.f,0.f,0.f,0.f};

  bf16x8_t wreg[LPT];
  auto loadWreg = [&](int ch){
    const long base = (long)(c_off + ch)*NCT*64;
    #pragma unroll
    for (int i = 0; i < LPT; i++){
      int idx = tid + i*256;
      wreg[i] = (idx < NCT*64) ? fh[base + idx] : fl[base + idx - NCT*64];
    }
  };
  auto writeW = [&](int buf){
    bf16x8_t* wflat = &wbuf[buf][0][0];
    #pragma unroll
    for (int i = 0; i < LPT; i++) wflat[tid + i*256] = wreg[i];
  };

  float4 Areg0[2], Areg1[2];
  auto loadA = [&](int ch, float4 (&A)[2]){
    int kk = ch / CPS;
    int cc = ch - kk*CPS;
    int k  = k0 + kk;
    const float* Xk = (k == 0) ? X0 : AR + (size_t)((k-1) % nfit)*slice;
    const float* ap = Xk + (long)(r0 + ra)*CI + cc*32 + k8;
    A[0] = *(const float4*)(ap);
    A[1] = *(const float4*)(ap + 4);
  };
  auto computeC = [&](float4 (&A)[2], int buf){
    float av[8] = {A[0].x, A[0].y, A[0].z, A[0].w, A[1].x, A[1].y, A[1].z, A[1].w};
    bf16x8_t ah, al;
    #pragma unroll
    for (int i = 0; i < 8; i++){
      unsigned short hh = f2bf(av[i]);
      float hf = __uint_as_float(((unsigned int)hh) << 16);
      ah[i] = (short)hh;
      al[i] = (short)f2bf(av[i] - hf);
    }
    #pragma unroll
    for (int ct = 0; ct < NCT; ct++){
      bf16x8_t wh = wbuf[buf][ct][lane];
      bf16x8_t wl = wbuf[buf][NCT + ct][lane];
      accv[ct] = __builtin_amdgcn_mfma_f32_16x16x32_bf16(ah, wh, accv[ct], 0, 0, 0);
      accv[ct] = __builtin_amdgcn_mfma_f32_16x16x32_bf16(al, wh, accv[ct], 0, 0, 0);
      accv[ct] = __builtin_amdgcn_mfma_f32_16x16x32_bf16(ah, wl, accv[ct], 0, 0, 0);
    }
  };

  // prologue: stage chunk 0
  loadWreg(0);
  loadA(0, Areg0);
  writeW(0);
  __syncthreads();

  int cur = 0;
  for (int ch = 0; ch < nch; ch++){
    if (ch + 1 < nch){
      loadWreg(ch + 1);
      loadA(ch + 1, (ch & 1) ? Areg0 : Areg1);
    }
    computeC((ch & 1) ? Areg1 : Areg0, cur);
    if (ch + 1 < nch) writeW(cur ^ 1);
    __syncthreads();
    cur ^= 1;
  }

  // C/D layout: col = lane&15, row = (lane>>4)*4 + j   [m89-verified]
  const int rl  = (lane >> 4)*4;
  const int cb2 = lane & 15;
  #pragma unroll
  for (int ct = 0; ct < NCT; ct++){
    const int col = ct*16 + cb2;
    const float bia = do_elu ? bias[col] : 0.f;
    #pragma unroll
    for (int j = 0; j < 4; j++){
      float* cp = C + (r0 + rl + j)*CO + col;
      float v = accv[ct][j];
      if (acc) v += *cp;
      if (do_elu) v = elu_f(v + bia);
      *cp = v;
    }
  }
}

// ---------------- MFMA GEMM, independent tiles (large-M shapes) ----------------
template<int CI, int CO, int MT, int TPB>
__global__ __launch_bounds__(TPB) void gemm_mfma(
    const float* X0, const float* __restrict__ AR,
    const bf16x8_t* __restrict__ fh, const bf16x8_t* __restrict__ fl,
    const float* __restrict__ bias, float* C,
    int k0, int nk, int nfit, long slice, int acc, int do_elu){
  constexpr int NCT = CO/16;
  constexpr int CPS = CI/32;
  constexpr int WPB = TPB/64;
  const int lane = threadIdx.x & 63;
  const int wv   = threadIdx.x >> 6;
  const long r0  = ((long)blockIdx.x*WPB + wv) * (16*MT);
  const int ra   = lane & 15;
  const int k8   = (lane >> 4)*8;
  const int c_off = k0*CPS;
  const int nch = nk*CPS;

  f32x4_t accv[MT][NCT];
  #pragma unroll
  for (int t = 0; t < MT; t++)
    #pragma unroll
    for (int ct = 0; ct < NCT; ct++) accv[t][ct] = (f32x4_t){0.f,0.f,0.f,0.f};

  float4 Abuf0[MT][2], Abuf1[MT][2];

  auto loadA = [&](int ch, float4 (&A)[MT][2]){
    int kk = ch / CPS;
    int cc = ch - kk*CPS;
    int k  = k0 + kk;
    const float* Xk = (k == 0) ? X0 : AR + (size_t)((k-1) % nfit)*slice;
    const float* ap = Xk + (long)(r0 + ra)*CI + cc*32 + k8;
    #pragma unroll
    for (int t = 0; t < MT; t++){
      A[t][0] = *(const float4*)(ap + (long)t*16*CI);
      A[t][1] = *(const float4*)(ap + (long)t*16*CI + 4);
    }
  };

  auto computeC = [&](float4 (&A)[MT][2], int ch){
    bf16x8_t ah[MT], al[MT];
    #pragma unroll
    for (int t = 0; t < MT; t++){
      float av[8] = {A[t][0].x, A[t][0].y, A[t][0].z, A[t][0].w,
                     A[t][1].x, A[t][1].y, A[t][1].z, A[t][1].w};
      #pragma unroll
      for (int i = 0; i < 8; i++){
        unsigned short hh = f2bf(av[i]);
        float hf = __uint_as_float(((unsigned int)hh) << 16);
        ah[t][i] = (short)hh;
        al[t][i] = (short)f2bf(av[i] - hf);
      }
    }
    const long cb = ((long)(c_off + ch)*NCT)*64 + lane;
    #pragma unroll
    for (int ct = 0; ct < NCT; ct++){
      bf16x8_t wh = fh[cb + ct*64];
      bf16x8_t wl = fl[cb + ct*64];
      #pragma unroll
      for (int t = 0; t < MT; t++){
        accv[t][ct] = __builtin_amdgcn_mfma_f32_16x16x32_bf16(ah[t], wh, accv[t][ct], 0, 0, 0);
        accv[t][ct] = __builtin_amdgcn_mfma_f32_16x16x32_bf16(al[t], wh, accv[t][ct], 0, 0, 0);
        accv[t][ct] = __builtin_amdgcn_mfma_f32_16x16x32_bf16(ah[t], wl, accv[t][ct], 0, 0, 0);
      }
    }
  };

  loadA(0, Abuf0);
  int ch = 0;
  while (true){
    if (ch + 1 < nch) loadA(ch + 1, Abuf1);
    computeC(Abuf0, ch);
    if (++ch >= nch) break;
    if (ch + 1 < nch) loadA(ch + 1, Abuf0);
    computeC(Abuf1, ch);
    if (++ch >= nch) break;
  }

  const int rl  = (lane >> 4)*4;
  const int cb2 = lane & 15;
  #pragma unroll
  for (int t = 0; t < MT; t++){
    #pragma unroll
    for (int ct = 0; ct < NCT; ct++){
      const int col = ct*16 + cb2;
      const float bia = do_elu ? bias[col] : 0.f;
      #pragma unroll
      for (int j = 0; j < 4; j++){
        float* cp = C + (r0 + t*16 + rl + j)*CO + col;
        float v = accv[t][ct][j];
        if (acc) v += *cp;
        if (do_elu) v = elu_f(v + bia);
        *cp = v;
      }
    }
  }
}

// ---------------- VALU GEMM for CI==1 (level-0 conv1 only) ----------------
template<int CI, int CO, int RT>
__global__ __launch_bounds__(256) void gemm_multi(
    const float* X0, const float* __restrict__ AR,
    const float* __restrict__ W, const float* __restrict__ bias,
    float* C, int k0, int nk, int nfit, long slice, int acc, int do_elu){
  constexpr int TN = CO/16;
  constexpr int NW = CI*CO;
  extern __shared__ float ws[];

  const int tid = threadIdx.x;
  const int tc = tid & 15, tr = tid >> 4;
  const long r0 = (long)blockIdx.x*(16*RT) + (long)tr*RT;

  const float4* W4 = (const float4*)(W + (size_t)k0*NW);
  for (int i = tid; i < nk*NW/4; i += 256) ((float4*)ws)[i] = W4[i];
  __syncthreads();

  float accv[RT][TN];
  #pragma unroll
  for (int m = 0; m < RT; m++)
    #pragma unroll
    for (int j = 0; j < TN; j++) accv[m][j] = 0.f;

  #pragma unroll 1
  for (int kk = 0; kk < nk; kk++){
    int k = k0 + kk;
    const float* Ak = (k == 0) ? X0 : AR + (size_t)((k-1) % nfit)*slice;
    const float* wsl = ws + (size_t)kk*NW;
    const float* Ar = Ak + r0*CI;
    float am[RT];
    #pragma unroll
    for (int m = 0; m < RT; m += 4){
      float4 a = *(const float4*)(Ar + m);
      am[m] = a.x; am[m+1] = a.y; am[m+2] = a.z; am[m+3] = a.w;
    }
    const float* wr = &wsl[tc];
    #pragma unroll
    for (int j = 0; j < TN; j++){
      float wv = wr[j*16];
      #pragma unroll
      for (int m = 0; m < RT; m++)
        accv[m][j] = fmaf(am[m], wv, accv[m][j]);
    }
  }

  #pragma unroll
  for (int m = 0; m < RT; m++){
    float* Cr = C + (r0 + m)*CO;
    #pragma unroll
    for (int j = 0; j < TN; j++){
      int col = tc + j*16;
      float v = accv[m][j];
      if (acc) v += Cr[col];
      if (do_elu) v = elu_f(v + bias[col]);
      Cr[col] = v;
    }
  }
}

static void launch_gemm(const float* X0, const float* AR,
                        const bf16x8_t* fh, const bf16x8_t* fl,
                        const float* W, const float* bias, float* C,
                        long M, int Ci, int Co, int k0, int nk, int nfit,
                        long slice, int acc, int do_elu, hipStream_t st){
  if (Ci == 1){
    size_t sh = (size_t)nk * 32 * sizeof(float);
    gemm_multi<1,32,8><<<(int)(M/128), 256, sh, st>>>(
        X0, AR, W, bias, C, k0, nk, nfit, slice, acc, do_elu);
    return;
  }
  // large-M shape: independent 4-wave tiles, MT=2 (R6-best config)
  if (Ci == 32 && Co == 32){
    gemm_mfma<32,32,2,256><<<(int)(M/128), 256, 0, st>>>(
        X0, AR, fh, fl, bias, C, k0, nk, nfit, slice, acc, do_elu);
    return;
  }
  // small-M shapes: row-split waves + LDS-staged double-buffered W
#define GK(ci,co) \
  if (Ci == ci && Co == co){ \
    gemm_mfma_rs<ci,co><<<(int)(M/64), 256, 0, st>>>( \
        X0, AR, fh, fl, bias, C, k0, nk, nfit, slice, acc, do_elu); \
    return; }
  GK(32,64) GK(64,64) GK(64,128) GK(128,128)
#undef GK
}

// out2 [V,B,C] pre-bias -> skip (d_out, [B,V,C]), pooled -> nx [V/4,B,C],
// optional pooled -> pool_out (d_out, [B,V/4,C])
__global__ void epilogue_k(const float* __restrict__ out2, const float* __restrict__ bias,
                           float* __restrict__ skip_out, float* __restrict__ nx,
                           float* __restrict__ pool_out, int V, int C){
  long t = (long)blockIdx.x*256 + threadIdx.x;
  long total = (long)(V/4)*BB*C;
  if (t >= total) return;
  int  c  = (int)(t % C);
  long bv = t / C;
  int  b  = (int)(bv % BB);
  int  v2 = (int)(bv / BB);
  float bia = bias[c];
  float s = 0.f;
  for (int j = 0; j < 4; j++){
    long v = (long)4*v2 + j;
    float val = elu_f(out2[(v*BB + b)*C + c] + bia);
    skip_out[((long)b*V + v)*C + c] = val;
    s += val;
  }
  s *= 0.25f;
  nx[((long)v2*BB + b)*C + c] = s;
  if (pool_out) pool_out[((long)b*(V/4) + v2)*C + c] = s;
}

__global__ void guard_k(float* __restrict__ out0, int code){
  if (threadIdx.x == 0) out0[0] = 1.0e6f + (float)code;
}

// ---------------- host driver ----------------

static int ilog2(int x){ int l = 0; while ((1 << l) < x) l++; return l; }

static void run_cheb(const float* x0, float* arena, long slice, int nfit,
                     float* outC, const float* w, const float* bias,
                     const bf16x8_t* fh, const bf16x8_t* fl,
                     int V, int Ci, int Co, const int* rp, const int* cs, const float* vs,
                     hipStream_t stream){
  long M = (long)V*BB;
  int F4 = BB*Ci/4;
  int lf4 = ilog2(F4);
  long n4 = (long)V*F4;

  int k0 = 0;
  int g = (KCH < nfit + 1) ? KCH : nfit + 1;
  int next_k = 1;
  while (k0 < KCH){
    int kend = k0 + g;
    for (int k = next_k; k < kend; k++){
      float* dst = arena + (size_t)((k-1) % nfit)*slice;
      const float* src = (k >= 2) ? arena + (size_t)((k-2) % nfit)*slice : x0;
      const float* prv = (k >= 3) ? arena + (size_t)((k-3) % nfit)*slice
                                  : ((k == 2) ? x0 : nullptr);
      spmv_gather4<<<GRD(n4), 256, 0, stream>>>(rp, cs, vs, (const float4*)src,
                                                (const float4*)prv, (float4*)dst, V, lf4,
                                                (k == 1) ? 1.f : 2.f, (k == 1) ? 0.f : -1.f);
    }
    next_k = kend;
    launch_gemm(x0, arena, fh, fl, w, bias, outC, M, Ci, Co, k0, g, nfit, slice,
                (k0 > 0) ? 1 : 0, (bias && kend == KCH) ? 1 : 0, stream);
    k0 = kend;
    g = (KCH - k0 < nfit) ? (KCH - k0) : nfit;
  }
}

extern "C" void kernel_launch(void* const* d_in, const int* in_sizes, int n_in,
                              void* d_out, int out_size, void* d_ws, size_t ws_size,
                              hipStream_t stream){
  const float* x_in  = (const float*)d_in[0];
  const float* w1[3] = {(const float*)d_in[1], (const float*)d_in[8],  (const float*)d_in[15]};
  const float* b1[3] = {(const float*)d_in[2], (const float*)d_in[9],  (const float*)d_in[16]};
  const float* w2[3] = {(const float*)d_in[3], (const float*)d_in[10], (const float*)d_in[17]};
  const float* b2[3] = {(const float*)d_in[4], (const float*)d_in[11], (const float*)d_in[18]};
  const int*  rows[3]= {(const int*)d_in[5],   (const int*)d_in[12],   (const int*)d_in[19]};
  const int*  cols[3]= {(const int*)d_in[6],   (const int*)d_in[13],   (const int*)d_in[20]};
  const float* vals[3]={(const float*)d_in[7], (const float*)d_in[14], (const float*)d_in[21]};
  float* out = (float*)d_out;

  const int V[3] = {49152, 12288, 3072};
  const int E[3] = {393216, 98304, 24576};
  const int Ci1[3] = {1, 32, 64};
  const int Co1[3] = {32, 64, 128};

  // ---- workspace layout (fp32 units) ----
  float* wsf = (float*)d_ws;
  size_t off = 0;
  const size_t BUFSZ = (size_t)49152 * BB * 32;   // 12,582,912 floats
  float* BUF0 = wsf + off; off += BUFSZ;
  float* ARENA = wsf + off; off += 3*BUFSZ;       // contiguous slice arena
  float* NX   = wsf + off; off += (size_t)12288 * BB * 32;
  int* rp[3]; int* cs[3]; float* vsf[3];
  for (int i = 0; i < 3; i++){
    rp[i]  = (int*)(wsf + off); off += V[i] + 1;
    cs[i]  = (int*)(wsf + off); off += E[i];
    vsf[i] =        wsf + off;  off += E[i];
  }
  int* cntw = (int*)(wsf + off); off += 49152;
  int* bsum = (int*)(wsf + off); off += 64;
  int* rpw  = (int*)(wsf + off); off += 49152;
  off = (off + 3) & ~(size_t)3;                   // 16B-align fragment arena
  bf16x8_t* FR = (bf16x8_t*)(wsf + off);
  // frag sizes (short8 units): w2L0 1280, w1L1 2560, w2L1 5120, w1L2 10240, w2L2 20480
  const long FS[5] = {1280, 2560, 5120, 10240, 20480};
  bf16x8_t *fh_[5], *fl_[5];
  {
    long fo = 0;
    for (int i = 0; i < 5; i++){ fh_[i] = FR + fo; fl_[i] = FR + fo + FS[i]; fo += 2*FS[i]; }
    off += (size_t)(2*(1280+2560+5120+10240+20480)) * 4;   // short8 = 4 floats
  }
  if (ws_size < off * sizeof(float)) return;

  const long ARENA_F = (long)3*BUFSZ;

  // ---- W fragments (hi/lo bf16, MFMA layout) — once per launch ----
  wfrag_k<<<GRD(FS[0]), 256, 0, stream>>>(w2[0], fh_[0], fl_[0],  320,  32);
  wfrag_k<<<GRD(FS[1]), 256, 0, stream>>>(w1[1], fh_[1], fl_[1],  320,  64);
  wfrag_k<<<GRD(FS[2]), 256, 0, stream>>>(w2[1], fh_[2], fl_[2],  640,  64);
  wfrag_k<<<GRD(FS[3]), 256, 0, stream>>>(w1[2], fh_[3], fl_[3],  640, 128);
  wfrag_k<<<GRD(FS[4]), 256, 0, stream>>>(w2[2], fh_[4], fl_[4], 1280, 128);

  // ---- CSR build per level ----
  for (int i = 0; i < 3; i++){
    zero_k   <<<GRD(V[i]), 256, 0, stream>>>(cntw, V[i]);
    hist_g   <<<GRD(E[i]), 256, 0, stream>>>(rows[i], cntw, E[i]);
    int nb = (V[i] + 1023) / 1024;
    scan_blk <<<nb, 1024, 0, stream>>>(cntw, rp[i], bsum, V[i]);
    scan_top <<<1, 64, 0, stream>>>(bsum, nb);
    scan_add <<<GRD(V[i]), 256, 0, stream>>>(rp[i], rpw, bsum, V[i], E[i]);
    scatter_g<<<GRD(E[i]), 256, 0, stream>>>(rows[i], cols[i], vals[i],
                                             rpw, cs[i], vsf[i], E[i]);
  }

  // ---- level 0 input: [B,V] -> [V,B,1] ----
  transpose_in<<<GRD(BB*V[0]), 256, 0, stream>>>(x_in, NX, V[0]);

  const long OFF_OUT[4] = {0, 12582912, 18874368, 22020096};
  const int FH1[3] = {-1, 1, 3};   // frag index for w1 per level (-1 = VALU path)
  const int FH2[3] = { 0, 2, 4};   // frag index for w2 per level

  for (int lvl = 0; lvl < 3; lvl++){
    int Vv = V[lvl];
    int Ci = Ci1[lvl], Cm = Co1[lvl];

    // conv1: NX -> BUF0 (bias+ELU fused on last GEMM group)
    long slice1 = (long)Vv*BB*Ci;
    int nf1 = (int)(ARENA_F / slice1); if (nf1 > 9) nf1 = 9;
    const bf16x8_t* f1h = (FH1[lvl] >= 0) ? fh_[FH1[lvl]] : nullptr;
    const bf16x8_t* f1l = (FH1[lvl] >= 0) ? fl_[FH1[lvl]] : nullptr;
    run_cheb(NX, ARENA, slice1, nf1, BUF0, w1[lvl], b1[lvl], f1h, f1l,
             Vv, Ci, Cm, rp[lvl], cs[lvl], vsf[lvl], stream);

    // conv2: BUF0 -> BUF0 (in-place; per-wave rows disjoint)
    long slice2 = (long)Vv*BB*Cm;
    int nf2 = (int)(ARENA_F / slice2); if (nf2 > 9) nf2 = 9;
    run_cheb(BUF0, ARENA, slice2, nf2, BUF0, w2[lvl], nullptr,
             fh_[FH2[lvl]], fl_[FH2[lvl]],
             Vv, Cm, Cm, rp[lvl], cs[lvl], vsf[lvl], stream);

    long n2 = (long)(Vv/4) * BB * Cm;
    float* pool_out = (lvl == 2) ? (out + OFF_OUT[3]) : (float*)nullptr;
    epilogue_k<<<GRD(n2), 256, 0, stream>>>(BUF0, b2[lvl],
                                            out + OFF_OUT[lvl], NX, pool_out,
                                            Vv, Cm);
  }

  if (out_size != 22806528)
    guard_k<<<1, 64, 0, stream>>>(out, out_size % 4096);
}

// Round 12
// 1544.447 us; speedup vs baseline: 1.5045x; 1.4500x over previous
//
#include <hip/hip_runtime.h>
#include <math.h>

#define BB 8      // batch
#define KCH 10    // Chebyshev order
#define GRD(n) ((int)(((n) + 255) / 256))

typedef __attribute__((ext_vector_type(8))) short bf16x8_t;
typedef __attribute__((ext_vector_type(8))) unsigned short u16x8_t;
typedef __attribute__((ext_vector_type(4))) float f32x4_t;

__device__ __forceinline__ float elu_f(float x){ return x > 0.f ? x : expf(x) - 1.f; }

// float -> bf16 (RNE)
__device__ __forceinline__ unsigned short f2bf(float f){
  unsigned int u = __float_as_uint(f);
  u += 0x7FFFu + ((u >> 16) & 1u);
  return (unsigned short)(u >> 16);
}
__device__ __forceinline__ float bf2f(unsigned short h){
  return __uint_as_float((unsigned int)h << 16);
}

// x input [B,V] fp32 -> x0 [V,B] bf16
__global__ void transpose_in(const float* __restrict__ x, unsigned short* __restrict__ x0,
                             int V){
  int i = blockIdx.x*256 + threadIdx.x;
  if (i < BB*V){
    int b = i / V, v = i - b*V;
    x0[(long)v*BB + b] = f2bf(x[i]);
  }
}

// ---------------- CSR build (global atomics) ----------------

__global__ void zero_k(int* __restrict__ p, int n){
  int i = blockIdx.x*256 + threadIdx.x;
  if (i < n) p[i] = 0;
}

__global__ void hist_g(const int* __restrict__ rows, int* __restrict__ cnt, int E){
  int e = blockIdx.x*256 + threadIdx.x;
  if (e < E) atomicAdd(&cnt[rows[e]], 1);
}

__global__ void scan_blk(const int* __restrict__ cnt, int* __restrict__ rp,
                         int* __restrict__ bsum, int V){
  __shared__ int sh[1024];
  int tid = threadIdx.x;
  int i = blockIdx.x*1024 + tid;
  int v = (i < V) ? cnt[i] : 0;
  sh[tid] = v;
  __syncthreads();
  for (int off = 1; off < 1024; off <<= 1){
    int t = (tid >= off) ? sh[tid - off] : 0;
    __syncthreads();
    sh[tid] += t;
    __syncthreads();
  }
  if (i < V) rp[i] = sh[tid] - v;
  if (tid == 1023) bsum[blockIdx.x] = sh[1023];
}

__global__ void scan_top(int* __restrict__ bsum, int nb){
  if (threadIdx.x == 0){
    int run = 0;
    for (int b = 0; b < nb; b++){ int t = bsum[b]; bsum[b] = run; run += t; }
  }
}

__global__ void scan_add(int* __restrict__ rp, int* __restrict__ rpw,
                         const int* __restrict__ bsum, int V, int E){
  int i = blockIdx.x*256 + threadIdx.x;
  if (i < V){
    int v = rp[i] + bsum[i >> 10];
    rp[i] = v;
    rpw[i] = v;
  }
  if (i == 0) rp[V] = E;
}

__global__ void scatter_g(const int* __restrict__ rows, const int* __restrict__ cols,
                          const float* __restrict__ vals,
                          int* __restrict__ rpw, int* __restrict__ cs,
                          float* __restrict__ vs, int E){
  int e = blockIdx.x*256 + threadIdx.x;
  if (e < E){
    int r = rows[e];
    int pos = atomicAdd(&rpw[r], 1);
    if (pos >= 0 && pos < E){
      cs[pos] = cols[e];
      vs[pos] = vals[e];
    }
  }
}

// ---------------- SpMV on bf16 slices ----------------
// Slices [V][BB*Ci] bf16; thread handles 8 contiguous elems (16B).
// G8 = BB*Ci/8 groups per vertex row; lf8 = log2(G8).
__global__ __launch_bounds__(256) void spmv_bf16(
    const int* __restrict__ rp, const int* __restrict__ cs, const float* __restrict__ vs,
    const unsigned short* __restrict__ xin, const unsigned short* __restrict__ xprev,
    unsigned short* __restrict__ xout, int V, int lf8, float alpha, float beta){
  long t = (long)blockIdx.x*256 + threadIdx.x;
  if (t >= ((long)V << lf8)) return;
  int r  = (int)(t >> lf8);
  long eb = t*8;                      // element base of this 8-group
  long gof = eb - ((long)r << lf8)*8; // within-row elem offset
  int j0 = rp[r], j1 = rp[r+1];
  float acc[8] = {0.f,0.f,0.f,0.f,0.f,0.f,0.f,0.f};
  for (int j = j0; j < j1; j++){
    int   c = cs[j];
    float v = vs[j];
    u16x8_t g = *(const u16x8_t*)(xin + ((long)c << lf8)*8 + gof);
    #pragma unroll
    for (int i = 0; i < 8; i++) acc[i] = fmaf(v, bf2f(g[i]), acc[i]);
  }
  u16x8_t o;
  if (xprev){
    u16x8_t p = *(const u16x8_t*)(xprev + eb);
    #pragma unroll
    for (int i = 0; i < 8; i++) o[i] = f2bf(fmaf(beta, bf2f(p[i]), alpha*acc[i]));
  } else {
    #pragma unroll
    for (int i = 0; i < 8; i++) o[i] = f2bf(alpha*acc[i]);
  }
  *(u16x8_t*)(xout + eb) = o;
}

// ---------------- W fragment precompute (bf16 hi/lo, MFMA layout) ----------------
// Frag element (c, ct, lane, i) <- Wcat[c*32 + (lane>>4)*8 + i][ct*16 + (lane&15)]
// stored as short8 at index (c*NCT + ct)*64 + lane. KT = 10*CI.
__global__ void wfrag_k(const float* __restrict__ w, bf16x8_t* __restrict__ fh,
                        bf16x8_t* __restrict__ fl, int KT, int CO){
  int t = blockIdx.x*256 + threadIdx.x;
  int NCT = CO >> 4;
  int total = (KT >> 5) * NCT * 64;
  if (t >= total) return;
  int lane = t & 63;
  int rest = t >> 6;
  int ct = rest % NCT;
  int c  = rest / NCT;
  int col = ct*16 + (lane & 15);
  int kb  = c*32 + (lane >> 4)*8;
  bf16x8_t h, l;
  #pragma unroll
  for (int i = 0; i < 8; i++){
    float v = w[(long)(kb + i)*CO + col];
    unsigned short hh = f2bf(v);
    float hf = bf2f(hh);
    h[i] = (short)hh;
    l[i] = (short)f2bf(v - hf);
  }
  fh[t] = h; fl[t] = l;
}

// ---------------- MFMA GEMM, column-split, A+W double-buffered (small-M) -----
// One 16-row tile per block; wave wv owns CTW=NCT/4 column-tiles and walks all
// k-chunks. A is a direct bf16x8 fragment load (no conversion). No LDS.
// do_elu: write bf16 to CP (conv1 output); else f32 C with optional acc RMW.
template<int CI, int CO>
__global__ __launch_bounds__(256) void gemm_mfma_cs(
    const unsigned short* __restrict__ X0, const unsigned short* __restrict__ AR,
    const bf16x8_t* __restrict__ fh, const bf16x8_t* __restrict__ fl,
    const float* __restrict__ bias, float* __restrict__ C,
    unsigned short* __restrict__ CP,
    int k0, int nk, int nfit, long sliceE, int acc, int do_elu){
  constexpr int NCT = CO/16;
  constexpr int CTW = NCT/4;
  constexpr int CPS = CI/32;
  const int lane = threadIdx.x & 63;
  const int wv   = threadIdx.x >> 6;
  const long r0  = (long)blockIdx.x * 16;
  const int ra   = lane & 15;
  const int k8   = (lane >> 4)*8;
  const int c_off = k0*CPS;
  const int nch  = nk*CPS;
  const int ctbase = wv*CTW;

  f32x4_t accv[CTW];
  #pragma unroll
  for (int t = 0; t < CTW; t++) accv[t] = (f32x4_t){0.f,0.f,0.f,0.f};

  bf16x8_t A0, A1;
  bf16x8_t W0[CTW][2], W1[CTW][2];

  auto loadA = [&](int ch, bf16x8_t &A){
    int kk = ch / CPS;
    int cc = ch - kk*CPS;
    int k  = k0 + kk;
    const unsigned short* Xk = (k == 0) ? X0 : AR + (size_t)((k-1) % nfit)*sliceE;
    A = *(const bf16x8_t*)(Xk + (long)(r0 + ra)*CI + cc*32 + k8);
  };
  auto loadW = [&](int ch, bf16x8_t (&W)[CTW][2]){
    const long cb = ((long)(c_off + ch)*NCT)*64 + lane;
    #pragma unroll
    for (int t = 0; t < CTW; t++){
      W[t][0] = fh[cb + (ctbase + t)*64];
      W[t][1] = fl[cb + (ctbase + t)*64];
    }
  };
  auto computeC = [&](bf16x8_t &A, bf16x8_t (&W)[CTW][2]){
    #pragma unroll
    for (int t = 0; t < CTW; t++){
      accv[t] = __builtin_amdgcn_mfma_f32_16x16x32_bf16(A, W[t][0], accv[t], 0, 0, 0);
      accv[t] = __builtin_amdgcn_mfma_f32_16x16x32_bf16(A, W[t][1], accv[t], 0, 0, 0);
    }
  };

  loadA(0, A0); loadW(0, W0);
  int ch = 0;
  while (true){
    if (ch + 1 < nch){ loadA(ch + 1, A1); loadW(ch + 1, W1); }
    computeC(A0, W0);
    if (++ch >= nch) break;
    if (ch + 1 < nch){ loadA(ch + 1, A0); loadW(ch + 1, W0); }
    computeC(A1, W1);
    if (++ch >= nch) break;
  }

  // C/D layout: col = lane&15, row = (lane>>4)*4 + j   [m89-verified]
  const int rl  = (lane >> 4)*4;
  const int cb2 = lane & 15;
  #pragma unroll
  for (int t = 0; t < CTW; t++){
    const int col = (ctbase + t)*16 + cb2;
    const float bia = do_elu ? bias[col] : 0.f;
    #pragma unroll
    for (int j = 0; j < 4; j++){
      long idx = (r0 + rl + j)*CO + col;
      float v = accv[t][j];
      if (acc) v += C[idx];
      if (do_elu) CP[idx] = f2bf(elu_f(v + bia));
      else        C[idx] = v;
    }
  }
}

// ---------------- MFMA GEMM, independent tiles (level-0 conv2, 32x32) --------
template<int CI, int CO, int MT, int TPB>
__global__ __launch_bounds__(TPB) void gemm_mfma(
    const unsigned short* __restrict__ X0, const unsigned short* __restrict__ AR,
    const bf16x8_t* __restrict__ fh, const bf16x8_t* __restrict__ fl,
    const float* __restrict__ bias, float* __restrict__ C,
    unsigned short* __restrict__ CP,
    int k0, int nk, int nfit, long sliceE, int acc, int do_elu){
  constexpr int NCT = CO/16;
  constexpr int CPS = CI/32;
  constexpr int WPB = TPB/64;
  const int lane = threadIdx.x & 63;
  const int wv   = threadIdx.x >> 6;
  const long r0  = ((long)blockIdx.x*WPB + wv) * (16*MT);
  const int ra   = lane & 15;
  const int k8   = (lane >> 4)*8;
  const int c_off = k0*CPS;
  const int nch = nk*CPS;

  f32x4_t accv[MT][NCT];
  #pragma unroll
  for (int t = 0; t < MT; t++)
    #pragma unroll
    for (int ct = 0; ct < NCT; ct++) accv[t][ct] = (f32x4_t){0.f,0.f,0.f,0.f};

  bf16x8_t A0[MT], A1[MT];

  auto loadA = [&](int ch, bf16x8_t (&A)[MT]){
    int kk = ch / CPS;
    int cc = ch - kk*CPS;
    int k  = k0 + kk;
    const unsigned short* Xk = (k == 0) ? X0 : AR + (size_t)((k-1) % nfit)*sliceE;
    const unsigned short* ap = Xk + (long)(r0 + ra)*CI + cc*32 + k8;
    #pragma unroll
    for (int t = 0; t < MT; t++) A[t] = *(const bf16x8_t*)(ap + (long)t*16*CI);
  };

  auto computeC = [&](bf16x8_t (&A)[MT], int ch){
    const long cb = ((long)(c_off + ch)*NCT)*64 + lane;
    #pragma unroll
    for (int ct = 0; ct < NCT; ct++){
      bf16x8_t wh = fh[cb + ct*64];
      bf16x8_t wl = fl[cb + ct*64];
      #pragma unroll
      for (int t = 0; t < MT; t++){
        accv[t][ct] = __builtin_amdgcn_mfma_f32_16x16x32_bf16(A[t], wh, accv[t][ct], 0, 0, 0);
        accv[t][ct] = __builtin_amdgcn_mfma_f32_16x16x32_bf16(A[t], wl, accv[t][ct], 0, 0, 0);
      }
    }
  };

  loadA(0, A0);
  int ch = 0;
  while (true){
    if (ch + 1 < nch) loadA(ch + 1, A1);
    computeC(A0, ch);
    if (++ch >= nch) break;
    if (ch + 1 < nch) loadA(ch + 1, A0);
    computeC(A1, ch);
    if (++ch >= nch) break;
  }

  const int rl  = (lane >> 4)*4;
  const int cb2 = lane & 15;
  #pragma unroll
  for (int t = 0; t < MT; t++){
    #pragma unroll
    for (int ct = 0; ct < NCT; ct++){
      const int col = ct*16 + cb2;
      const float bia = do_elu ? bias[col] : 0.f;
      #pragma unroll
      for (int j = 0; j < 4; j++){
        long idx = (r0 + t*16 + rl + j)*CO + col;
        float v = accv[t][ct][j];
        if (acc) v += C[idx];
        if (do_elu) CP[idx] = f2bf(elu_f(v + bia));
        else        C[idx] = v;
      }
    }
  }
}

// ---------------- VALU GEMM for CI==1 (level-0 conv1 only) ----------------
template<int CI, int CO, int RT>
__global__ __launch_bounds__(256) void gemm_multi(
    const unsigned short* __restrict__ X0, const unsigned short* __restrict__ AR,
    const float* __restrict__ W, const float* __restrict__ bias,
    float* __restrict__ C, unsigned short* __restrict__ CP,
    int k0, int nk, int nfit, long sliceE, int acc, int do_elu){
  constexpr int TN = CO/16;
  constexpr int NW = CI*CO;
  extern __shared__ float ws[];

  const int tid = threadIdx.x;
  const int tc = tid & 15, tr = tid >> 4;
  const long r0 = (long)blockIdx.x*(16*RT) + (long)tr*RT;

  const float4* W4 = (const float4*)(W + (size_t)k0*NW);
  for (int i = tid; i < nk*NW/4; i += 256) ((float4*)ws)[i] = W4[i];
  __syncthreads();

  float accv[RT][TN];
  #pragma unroll
  for (int m = 0; m < RT; m++)
    #pragma unroll
    for (int j = 0; j < TN; j++) accv[m][j] = 0.f;

  #pragma unroll 1
  for (int kk = 0; kk < nk; kk++){
    int k = k0 + kk;
    const unsigned short* Ak = (k == 0) ? X0 : AR + (size_t)((k-1) % nfit)*sliceE;
    const float* wsl = ws + (size_t)kk*NW;
    u16x8_t a = *(const u16x8_t*)(Ak + r0);   // Ci==1: 8 rows contiguous
    float am[RT];
    #pragma unroll
    for (int m = 0; m < RT; m++) am[m] = bf2f(a[m]);
    const float* wr = &wsl[tc];
    #pragma unroll
    for (int j = 0; j < TN; j++){
      float wv = wr[j*16];
      #pragma unroll
      for (int m = 0; m < RT; m++)
        accv[m][j] = fmaf(am[m], wv, accv[m][j]);
    }
  }

  #pragma unroll
  for (int m = 0; m < RT; m++){
    #pragma unroll
    for (int j = 0; j < TN; j++){
      int col = tc + j*16;
      long idx = (r0 + m)*CO + col;
      float v = accv[m][j];
      if (acc) v += C[idx];
      if (do_elu) CP[idx] = f2bf(elu_f(v + bias[col]));
      else        C[idx] = v;
    }
  }
}

static void launch_gemm(const unsigned short* X0, const unsigned short* AR,
                        const bf16x8_t* fh, const bf16x8_t* fl,
                        const float* W, const float* bias, float* C, unsigned short* CP,
                        long M, int Ci, int Co, int k0, int nk, int nfit,
                        long sliceE, int acc, int do_elu, hipStream_t st){
  if (Ci == 1){
    size_t sh = (size_t)nk * 32 * sizeof(float);
    gemm_multi<1,32,8><<<(int)(M/128), 256, sh, st>>>(
        X0, AR, W, bias, C, CP, k0, nk, nfit, sliceE, acc, do_elu);
    return;
  }
  if (Ci == 32 && Co == 32){
    gemm_mfma<32,32,2,256><<<(int)(M/128), 256, 0, st>>>(
        X0, AR, fh, fl, bias, C, CP, k0, nk, nfit, sliceE, acc, do_elu);
    return;
  }
#define GK(ci,co) \
  if (Ci == ci && Co == co){ \
    gemm_mfma_cs<ci,co><<<(int)(M/16), 256, 0, st>>>( \
        X0, AR, fh, fl, bias, C, CP, k0, nk, nfit, sliceE, acc, do_elu); \
    return; }
  GK(32,64) GK(64,64) GK(64,128) GK(128,128)
#undef GK
}

// out2 (CBUF f32, [V,B,C] pre-bias) -> skip (d_out f32), pooled -> nxp bf16,
// optional pooled -> pool_out (d_out f32)
__global__ void epilogue_k(const float* __restrict__ out2, const float* __restrict__ bias,
                           float* __restrict__ skip_out, unsigned short* __restrict__ nxp,
                           float* __restrict__ pool_out, int V, int C){
  long t = (long)blockIdx.x*256 + threadIdx.x;
  long total = (long)(V/4)*BB*C;
  if (t >= total) return;
  int  c  = (int)(t % C);
  long bv = t / C;
  int  b  = (int)(bv % BB);
  int  v2 = (int)(bv / BB);
  float bia = bias[c];
  float s = 0.f;
  for (int j = 0; j < 4; j++){
    long v = (long)4*v2 + j;
    float val = elu_f(out2[(v*BB + b)*C + c] + bia);
    skip_out[((long)b*V + v)*C + c] = val;
    s += val;
  }
  s *= 0.25f;
  nxp[((long)v2*BB + b)*C + c] = f2bf(s);
  if (pool_out) pool_out[((long)b*(V/4) + v2)*C + c] = s;
}

__global__ void guard_k(float* __restrict__ out0, int code){
  if (threadIdx.x == 0) out0[0] = 1.0e6f + (float)code;
}

// ---------------- host driver ----------------

static int ilog2(int x){ int l = 0; while ((1 << l) < x) l++; return l; }

// One ChebConv on bf16 slices. outC = f32 partial buffer (conv2);
// CP != null (with bias) => final group writes bf16 (bias+ELU fused, conv1).
static void run_cheb(const unsigned short* x0, unsigned short* arena, long sliceE, int nfit,
                     float* outC, unsigned short* CP, const float* w, const float* bias,
                     const bf16x8_t* fh, const bf16x8_t* fl,
                     int V, int Ci, int Co, const int* rp, const int* cs, const float* vs,
                     hipStream_t stream){
  long M = (long)V*BB;
  int lf8 = ilog2(Ci);          // G8 = BB*Ci/8 = Ci (BB=8)
  long n8 = (long)V << lf8;

  int k0 = 0;
  int g = (KCH < nfit + 1) ? KCH : nfit + 1;
  int next_k = 1;
  while (k0 < KCH){
    int kend = k0 + g;
    for (int k = next_k; k < kend; k++){
      unsigned short* dst = arena + (size_t)((k-1) % nfit)*sliceE;
      const unsigned short* src = (k >= 2) ? arena + (size_t)((k-2) % nfit)*sliceE : x0;
      const unsigned short* prv = (k >= 3) ? arena + (size_t)((k-3) % nfit)*sliceE
                                           : ((k == 2) ? x0 : nullptr);
      spmv_bf16<<<GRD(n8), 256, 0, stream>>>(rp, cs, vs, src, prv, dst, V, lf8,
                                             (k == 1) ? 1.f : 2.f, (k == 1) ? 0.f : -1.f);
    }
    next_k = kend;
    int last = (kend == KCH) ? 1 : 0;
    launch_gemm(x0, arena, fh, fl, w, bias, outC, CP, M, Ci, Co, k0, g, nfit, sliceE,
                (k0 > 0) ? 1 : 0, (CP && last) ? 1 : 0, stream);
    k0 = kend;
    g = (KCH - k0 < nfit) ? (KCH - k0) : nfit;
  }
}

extern "C" void kernel_launch(void* const* d_in, const int* in_sizes, int n_in,
                              void* d_out, int out_size, void* d_ws, size_t ws_size,
                              hipStream_t stream){
  const float* x_in  = (const float*)d_in[0];
  const float* w1[3] = {(const float*)d_in[1], (const float*)d_in[8],  (const float*)d_in[15]};
  const float* b1[3] = {(const float*)d_in[2], (const float*)d_in[9],  (const float*)d_in[16]};
  const float* w2[3] = {(const float*)d_in[3], (const float*)d_in[10], (const float*)d_in[17]};
  const float* b2[3] = {(const float*)d_in[4], (const float*)d_in[11], (const float*)d_in[18]};
  const int*  rows[3]= {(const int*)d_in[5],   (const int*)d_in[12],   (const int*)d_in[19]};
  const int*  cols[3]= {(const int*)d_in[6],   (const int*)d_in[13],   (const int*)d_in[20]};
  const float* vals[3]={(const float*)d_in[7], (const float*)d_in[14], (const float*)d_in[21]};
  float* out = (float*)d_out;

  const int V[3] = {49152, 12288, 3072};
  const int E[3] = {393216, 98304, 24576};
  const int Ci1[3] = {1, 32, 64};
  const int Co1[3] = {32, 64, 128};

  // ---- workspace layout (fp32 units for region sizing) ----
  float* wsf = (float*)d_ws;
  size_t off = 0;
  const size_t BUFSZ = (size_t)49152 * BB * 32;   // 12,582,912 elems
  float* CBUF = wsf + off; off += BUFSZ;                                 // f32 GEMM partials
  unsigned short* X0P = (unsigned short*)(wsf + off); off += BUFSZ/2;    // conv1 out (bf16)
  unsigned short* ARENA = (unsigned short*)(wsf + off); off += 3*BUFSZ;  // slice arena bf16
  unsigned short* NXP = (unsigned short*)(wsf + off); off += (size_t)12288*BB*32/2;
  int* rp[3]; int* cs[3]; float* vsf[3];
  for (int i = 0; i < 3; i++){
    rp[i]  = (int*)(wsf + off); off += V[i] + 1;
    cs[i]  = (int*)(wsf + off); off += E[i];
    vsf[i] =        wsf + off;  off += E[i];
  }
  int* cntw = (int*)(wsf + off); off += 49152;
  int* bsum = (int*)(wsf + off); off += 64;
  int* rpw  = (int*)(wsf + off); off += 49152;
  off = (off + 3) & ~(size_t)3;                   // 16B-align fragment arena
  bf16x8_t* FR = (bf16x8_t*)(wsf + off);
  // frag sizes (short8 units): w2L0 1280, w1L1 2560, w2L1 5120, w1L2 10240, w2L2 20480
  const long FS[5] = {1280, 2560, 5120, 10240, 20480};
  bf16x8_t *fh_[5], *fl_[5];
  {
    long fo = 0;
    for (int i = 0; i < 5; i++){ fh_[i] = FR + fo; fl_[i] = FR + fo + FS[i]; fo += 2*FS[i]; }
    off += (size_t)(2*(1280+2560+5120+10240+20480)) * 4;   // short8 = 4 floats
  }
  if (ws_size < off * sizeof(float)) return;

  const long ARENA_E = (long)6*BUFSZ;   // arena capacity in bf16 elems

  // ---- W fragments (hi/lo bf16, MFMA layout) — once per launch ----
  wfrag_k<<<GRD(FS[0]), 256, 0, stream>>>(w2[0], fh_[0], fl_[0],  320,  32);
  wfrag_k<<<GRD(FS[1]), 256, 0, stream>>>(w1[1], fh_[1], fl_[1],  320,  64);
  wfrag_k<<<GRD(FS[2]), 256, 0, stream>>>(w2[1], fh_[2], fl_[2],  640,  64);
  wfrag_k<<<GRD(FS[3]), 256, 0, stream>>>(w1[2], fh_[3], fl_[3],  640, 128);
  wfrag_k<<<GRD(FS[4]), 256, 0, stream>>>(w2[2], fh_[4], fl_[4], 1280, 128);

  // ---- CSR build per level ----
  for (int i = 0; i < 3; i++){
    zero_k   <<<GRD(V[i]), 256, 0, stream>>>(cntw, V[i]);
    hist_g   <<<GRD(E[i]), 256, 0, stream>>>(rows[i], cntw, E[i]);
    int nb = (V[i] + 1023) / 1024;
    scan_blk <<<nb, 1024, 0, stream>>>(cntw, rp[i], bsum, V[i]);
    scan_top <<<1, 64, 0, stream>>>(bsum, nb);
    scan_add <<<GRD(V[i]), 256, 0, stream>>>(rp[i], rpw, bsum, V[i], E[i]);
    scatter_g<<<GRD(E[i]), 256, 0, stream>>>(rows[i], cols[i], vals[i],
                                             rpw, cs[i], vsf[i], E[i]);
  }

  // ---- level 0 input: [B,V] f32 -> [V,B,1] bf16 ----
  transpose_in<<<GRD(BB*V[0]), 256, 0, stream>>>(x_in, NXP, V[0]);

  const long OFF_OUT[4] = {0, 12582912, 18874368, 22020096};
  const int FH1[3] = {-1, 1, 3};   // frag index for w1 per level (-1 = VALU path)
  const int FH2[3] = { 0, 2, 4};   // frag index for w2 per level

  for (int lvl = 0; lvl < 3; lvl++){
    int Vv = V[lvl];
    int Ci = Ci1[lvl], Cm = Co1[lvl];

    // conv1: NXP (bf16) -> X0P (bf16; bias+ELU fused on last GEMM group)
    long s1 = (long)Vv*BB*Ci;
    int nf1 = (int)(ARENA_E / s1); if (nf1 > 9) nf1 = 9;
    const bf16x8_t* f1h = (FH1[lvl] >= 0) ? fh_[FH1[lvl]] : nullptr;
    const bf16x8_t* f1l = (FH1[lvl] >= 0) ? fl_[FH1[lvl]] : nullptr;
    run_cheb(NXP, ARENA, s1, nf1, CBUF, X0P, w1[lvl], b1[lvl], f1h, f1l,
             Vv, Ci, Cm, rp[lvl], cs[lvl], vsf[lvl], stream);

    // conv2: X0P (bf16) -> CBUF (f32 raw; epilogue applies bias+ELU+pool)
    long s2 = (long)Vv*BB*Cm;
    int nf2 = (int)(ARENA_E / s2); if (nf2 > 9) nf2 = 9;
    run_cheb(X0P, ARENA, s2, nf2, CBUF, nullptr, w2[lvl], nullptr,
             fh_[FH2[lvl]], fl_[FH2[lvl]],
             Vv, Cm, Cm, rp[lvl], cs[lvl], vsf[lvl], stream);

    long n2 = (long)(Vv/4) * BB * Cm;
    float* pool_out = (lvl == 2) ? (out + OFF_OUT[3]) : (float*)nullptr;
    epilogue_k<<<GRD(n2), 256, 0, stream>>>(CBUF, b2[lvl],
                                            out + OFF_OUT[lvl], NXP, pool_out,
                                            Vv, Cm);
  }

  if (out_size != 22806528)
    guard_k<<<1, 64, 0, stream>>>(out, out_size % 4096);
}